// Round 12
// baseline (502.403 us; speedup 1.0000x reference)
//
#include <hip/hip_runtime.h>
#include <math.h>

#define NODES 30000
#define EDGES 600000
#define QS_W 512     // fp16 row: [q 256 | s 256]
#define K_W 256      // fp16 k row: 256 ushorts (512 B)
#define KV_W 256     // fp8 v row: 256 bytes
#define OUT_W 256
#define BN_EPS 1e-5f

typedef _Float16 f16x8 __attribute__((ext_vector_type(8)));
typedef _Float16 half2t __attribute__((ext_vector_type(2)));
typedef float f32x2 __attribute__((ext_vector_type(2)));
typedef __attribute__((ext_vector_type(4))) float f32x4;

__device__ __forceinline__ unsigned short f2h(float f) {
    union { _Float16 h; unsigned short u; } v;
    v.h = (_Float16)f;                      // v_cvt_f16_f32 (RNE)
    return v.u;
}
__device__ __forceinline__ float h2f(unsigned short u) {
    union { unsigned short u; _Float16 h; } v; v.u = u;
    return (float)v.h;
}
__device__ __forceinline__ half2t u2h2(unsigned int u) {
    union { unsigned int u; half2t h; } v; v.u = u;
    return v.h;
}

__device__ __forceinline__ float fdot2(half2t a, half2t b, float c) {
#if __has_builtin(__builtin_amdgcn_fdot2)
    return __builtin_amdgcn_fdot2(a, b, c, false);
#else
    return fmaf((float)a.x, (float)b.x, fmaf((float)a.y, (float)b.y, c));
#endif
}

// ---- OCP e4m3 pack/unpack (HW cvt when available; exact bit-math fallback) ----
// fallback math: e4m3 bits<<7 reinterpreted as fp16 = value * 2^-8 (exact incl. denorms)

__device__ __forceinline__ void dec8(uint2 w, float* f) {
#if __has_builtin(__builtin_amdgcn_cvt_pk_f32_fp8)
    f32x2 a = __builtin_amdgcn_cvt_pk_f32_fp8((int)w.x, false);
    f32x2 b = __builtin_amdgcn_cvt_pk_f32_fp8((int)w.x, true);
    f32x2 c = __builtin_amdgcn_cvt_pk_f32_fp8((int)w.y, false);
    f32x2 d = __builtin_amdgcn_cvt_pk_f32_fp8((int)w.y, true);
    f[0] = a.x; f[1] = a.y; f[2] = b.x; f[3] = b.y;
    f[4] = c.x; f[5] = c.y; f[6] = d.x; f[7] = d.y;
#else
    #pragma unroll
    for (int j = 0; j < 8; j++) {
        unsigned int byte = ((j < 4 ? w.x : w.y) >> ((j & 3) * 8)) & 0xFF;
        unsigned short h = (unsigned short)(((byte & 0x80u) << 8) | ((byte & 0x7Fu) << 7));
        f[j] = h2f(h) * 256.0f;
    }
#endif
}

__device__ __forceinline__ uint2 enc8(uint4 w) {
    float f[8];
    f[0] = h2f((unsigned short)(w.x & 0xffff)); f[1] = h2f((unsigned short)(w.x >> 16));
    f[2] = h2f((unsigned short)(w.y & 0xffff)); f[3] = h2f((unsigned short)(w.y >> 16));
    f[4] = h2f((unsigned short)(w.z & 0xffff)); f[5] = h2f((unsigned short)(w.z >> 16));
    f[6] = h2f((unsigned short)(w.w & 0xffff)); f[7] = h2f((unsigned short)(w.w >> 16));
    uint2 r;
#if __has_builtin(__builtin_amdgcn_cvt_pk_fp8_f32)
    int lo = 0, hi = 0;
    lo = __builtin_amdgcn_cvt_pk_fp8_f32(f[0], f[1], lo, false);
    lo = __builtin_amdgcn_cvt_pk_fp8_f32(f[2], f[3], lo, true);
    hi = __builtin_amdgcn_cvt_pk_fp8_f32(f[4], f[5], hi, false);
    hi = __builtin_amdgcn_cvt_pk_fp8_f32(f[6], f[7], hi, true);
    r.x = (unsigned)lo; r.y = (unsigned)hi;
#else
    unsigned b[8];
    #pragma unroll
    for (int j = 0; j < 8; j++) {
        unsigned short hb = f2h(f[j] * 0.00390625f);   // *2^-8
        unsigned m = hb & 0x7fffu;
        unsigned rr = m + 0x3Fu + ((m >> 7) & 1u);     // RNE on dropped 7 bits
        b[j] = ((hb >> 8) & 0x80u) | ((rr >> 7) & 0x7Fu);
    }
    r.x = b[0] | (b[1] << 8) | (b[2] << 16) | (b[3] << 24);
    r.y = b[4] | (b[5] << 8) | (b[6] << 16) | (b[7] << 24);
#endif
    return r;
}

// butterfly add via DPP (VALU pipe). 0xB1=xor1, 0x4E=xor2, 0x141=row_half_mirror(^4 after folds)
template<int CTRL>
__device__ __forceinline__ float dpp_xor_add(float x) {
    int xi = __builtin_bit_cast(int, x);
    int yi = __builtin_amdgcn_mov_dpp(xi, CTRL, 0xF, 0xF, true);
    return x + __builtin_bit_cast(float, yi);
}

typedef const __attribute__((address_space(1))) void* gas_p;
typedef __attribute__((address_space(3))) void* las_p;
__device__ __forceinline__ void gload_lds16(const void* g, void* l) {
    __builtin_amdgcn_global_load_lds((gas_p)g, (las_p)l, 16, 0, 0);
}

// ---------------- init: zero deg + BN sum arrays (replaces 2 memset dispatches) ----------------

__global__ __launch_bounds__(256) void k_init(int* __restrict__ deg, float* __restrict__ sums) {
    int i = blockIdx.x * 256 + threadIdx.x;
    if (i < NODES) deg[i] = 0;
    if (blockIdx.x == 0) {
        // 1024 floats (sum1|sq1|sum2|sq2 contiguous), 4 per thread
        #pragma unroll
        for (int j = 0; j < 4; j++) sums[threadIdx.x * 4 + j] = 0.f;
    }
}

// ---------------- CSR build ----------------

__global__ __launch_bounds__(256) void k_count(const int* __restrict__ ei, int* __restrict__ deg) {
    int e = blockIdx.x * 256 + threadIdx.x;
    if (e < EDGES) atomicAdd(&deg[ei[EDGES + e]], 1);   // dst row
}

// single-block exclusive scan over all 30000 degrees (replaces blocksum+scanb+localscan).
// 1024 threads x 30 nodes each; two passes over deg (second pass L1/L2-hot) to keep
// everything in registers (no runtime-indexed local arrays -> no scratch, rule #20).
__global__ __launch_bounds__(1024) void k_scan1(const int* __restrict__ deg,
                                                int* __restrict__ rowptr,
                                                int* __restrict__ cursor) {
    __shared__ int sh[1024];
    int t = threadIdx.x;
    int base = t * 30;                       // 1024*30 = 30720 >= 30000
    int cnt = NODES - base;
    if (cnt < 0) cnt = 0;
    if (cnt > 30) cnt = 30;
    int sum = 0;
    for (int i = 0; i < cnt; i++) sum += deg[base + i];
    sh[t] = sum;
    __syncthreads();
    for (int off = 1; off < 1024; off <<= 1) {
        int add = (t >= off) ? sh[t - off] : 0;
        __syncthreads();
        sh[t] += add;
        __syncthreads();
    }
    int run = sh[t] - sum;                   // exclusive base for this thread's range
    for (int i = 0; i < cnt; i++) {
        rowptr[base + i] = run;
        cursor[base + i] = run;
        run += deg[base + i];                // re-read: L1-hot
    }
}

__global__ __launch_bounds__(256) void k_fill(const int* __restrict__ ei, int* __restrict__ cursor,
                                              int* __restrict__ csr_src) {
    int e = blockIdx.x * 256 + threadIdx.x;
    if (e < EDGES) {
        int s = ei[e];
        int d = ei[EDGES + e];
        int slot = atomicAdd(&cursor[d], 1);
        csr_src[slot] = s;
    }
}

// ---------------- fused cast: blocks [0,128) = W transpose-cast; rest = A cast ----------------
// W path: values bit-identical to the original k_castW2 (coalesced via 64x64 LDS tile).
// A path: fp32 x -> fp16 abuf, 8 elems/thread.

__global__ __launch_bounds__(256) void k_castAW(
    const float* __restrict__ x, unsigned short* __restrict__ abuf,
    const float* __restrict__ Wa0, const float* __restrict__ Wa1,
    const float* __restrict__ Wa2, const float* __restrict__ Wa3,
    const float* __restrict__ Ba0, const float* __restrict__ Ba1,
    const float* __restrict__ Ba2, const float* __restrict__ Ba3,
    const float* __restrict__ Wb0, const float* __restrict__ Wb1,
    const float* __restrict__ Wb2, const float* __restrict__ Wb3,
    const float* __restrict__ Bb0, const float* __restrict__ Bb1,
    const float* __restrict__ Bb2, const float* __restrict__ Bb3,
    unsigned short* __restrict__ Wt1, float* __restrict__ bf1,
    unsigned short* __restrict__ Wt2, float* __restrict__ bf2)
{
    __shared__ float tile[64][65];
    int b = blockIdx.x;
    if (b >= 128) {
        // ---- A cast: item index over NODES*256/8 = 960000
        int i = (b - 128) * 256 + threadIdx.x;
        if (i >= NODES * 256 / 8) return;
        const float4* p = (const float4*)(x + (size_t)i * 8);
        float4 v0 = p[0], v1 = p[1];
        ushort4 o0, o1;
        o0.x = f2h(v0.x); o0.y = f2h(v0.y); o0.z = f2h(v0.z); o0.w = f2h(v0.w);
        o1.x = f2h(v1.x); o1.y = f2h(v1.y); o1.z = f2h(v1.z); o1.w = f2h(v1.w);
        ushort4* q = (ushort4*)(abuf + (size_t)i * 8);
        q[0] = o0; q[1] = o1;
        return;
    }
    // ---- W transpose-cast
    int layer = b >> 6;
    int wsel = (b >> 4) & 3;
    int kt = (b >> 2) & 3;   // k-row tile of W (64 rows)
    int ct = b & 3;          // col tile of W (64 cols)
    const float* W; const float* Bv;
    if (layer == 0) {
        W  = (wsel == 0) ? Wa0 : (wsel == 1) ? Wa1 : (wsel == 2) ? Wa2 : Wa3;
        Bv = (wsel == 0) ? Ba0 : (wsel == 1) ? Ba1 : (wsel == 2) ? Ba2 : Ba3;
    } else {
        W  = (wsel == 0) ? Wb0 : (wsel == 1) ? Wb1 : (wsel == 2) ? Wb2 : Wb3;
        Bv = (wsel == 0) ? Bb0 : (wsel == 1) ? Bb1 : (wsel == 2) ? Bb2 : Bb3;
    }
    unsigned short* Wt = (layer == 0) ? Wt1 : Wt2;
    float* bfused = (layer == 0) ? bf1 : bf2;

    int t = threadIdx.x;
    int tr = t >> 4;           // 0..15
    int tc4 = (t & 15) * 4;    // 0,4,...,60
    #pragma unroll
    for (int r = 0; r < 64; r += 16) {
        float4 v = *(const float4*)&W[(size_t)(kt * 64 + tr + r) * 256 + ct * 64 + tc4];
        tile[tr + r][tc4 + 0] = v.x;
        tile[tr + r][tc4 + 1] = v.y;
        tile[tr + r][tc4 + 2] = v.z;
        tile[tr + r][tc4 + 3] = v.w;
    }
    __syncthreads();
    #pragma unroll
    for (int r = 0; r < 64; r += 16) {
        int nr = tr + r;                       // col-local of W == row-local of Wt
        ushort4 o;
        o.x = f2h(tile[tc4 + 0][nr]);
        o.y = f2h(tile[tc4 + 1][nr]);
        o.z = f2h(tile[tc4 + 2][nr]);
        o.w = f2h(tile[tc4 + 3][nr]);
        *(ushort4*)&Wt[(size_t)(wsel * 256 + ct * 64 + nr) * 256 + kt * 64 + tc4] = o;
    }
    if (kt == 0 && t < 64) bfused[wsel * 256 + ct * 64 + t] = Bv[ct * 64 + t];
}

// ---------------- fp16 MFMA GEMM; XCD-chunked block swizzle; epilogue: QS/K16/V8 ----------------
// 1880 flat blocks = 235 row x 8 col; xcd = bid%8 owns a contiguous sbid chunk (bijective).

#define CS 136   // padded LDS stride (ushorts) for the 128x128 C tile

__global__ __launch_bounds__(256) void k_gemm_f16(
    const unsigned short* __restrict__ A,
    const unsigned short* __restrict__ Wt,
    const float* __restrict__ bias,
    unsigned short* __restrict__ QS,
    unsigned short* __restrict__ K16,
    unsigned char* __restrict__ V8, int M)
{
    __shared__ unsigned short sbuf[128 * CS];   // 34,816 B; unions staging (32KB) and epilogue
    unsigned short* As = sbuf;                  // 128*64
    unsigned short* Bs = sbuf + 8192;           // 128*64
    int tid = threadIdx.x;
    int lane = tid & 63;
    int wave = tid >> 6;
    int wm = wave & 1, wn = wave >> 1;      // 2x2 waves -> 64x64 each

    // XCD-chunked swizzle: xcd = bid%8 owns sbid range [xcd*235, (xcd+1)*235)
    int bid = blockIdx.x;
    int sbid = (bid & 7) * 235 + (bid >> 3);
    int row0 = (sbid >> 3) * 128;           // row-block   (0..234)
    int n0 = (sbid & 7) * 128;              // col-block in fused 1024-col space

    f32x4 acc[4][4] = {};

    for (int k0 = 0; k0 < 256; k0 += 64) {
        #pragma unroll
        for (int w = 0; w < 4; w++) {
            int c = w * 256 + tid;
            int row = c >> 3;
            int cole = (c & 7) * 8;
            int ar = row0 + row; if (ar >= M) ar = M - 1;
            gload_lds16(&A[(size_t)ar * 256 + k0 + cole], &As[w * 2048 + tid * 8]);
            gload_lds16(&Wt[(size_t)(n0 + row) * 256 + k0 + cole], &Bs[w * 2048 + tid * 8]);
        }
        __syncthreads();
        int rsel = lane & 15;
        int kq = (lane >> 4) * 8;
        #pragma unroll
        for (int kh = 0; kh < 2; kh++) {
            f16x8 af[4], bfr[4];
            #pragma unroll
            for (int t = 0; t < 4; t++) {
                af[t]  = *reinterpret_cast<const f16x8*>(&As[(wm * 64 + t * 16 + rsel) * 64 + kh * 32 + kq]);
                bfr[t] = *reinterpret_cast<const f16x8*>(&Bs[(wn * 64 + t * 16 + rsel) * 64 + kh * 32 + kq]);
            }
            #pragma unroll
            for (int mt = 0; mt < 4; mt++)
                #pragma unroll
                for (int nt = 0; nt < 4; nt++)
                    acc[mt][nt] = __builtin_amdgcn_mfma_f32_16x16x32_f16(af[mt], bfr[nt], acc[mt][nt], 0, 0, 0);
        }
        __syncthreads();
    }

    // epilogue: stage fp16(+bias) tile into padded LDS (C/D map: col=lane&15, row=(lane>>4)*4+reg)
    int crow = (lane >> 4) * 4;
    int ccol = lane & 15;
    #pragma unroll
    for (int mt = 0; mt < 4; mt++) {
        int lrow = wm * 64 + mt * 16 + crow;
        #pragma unroll
        for (int nt = 0; nt < 4; nt++) {
            int lcol = wn * 64 + nt * 16 + ccol;
            float bv = bias[n0 + lcol];
            #pragma unroll
            for (int r = 0; r < 4; r++)
                sbuf[(lrow + r) * CS + lcol] = f2h(acc[mt][nt][r] + bv);
        }
    }
    __syncthreads();
    int chunk = tid & 15;
    int rbase = tid >> 4;
    if (n0 < 256 || n0 >= 768) {
        // q (cols 0..255) or s (768..1023) -> fp16 qs rows [q|s]
        int cbase = (n0 < 256) ? n0 : (n0 - 512);
        #pragma unroll
        for (int g = 0; g < 8; g++) {
            int row_l = g * 16 + rbase;
            int gr = row0 + row_l;
            if (gr < M) {
                uint4 val = *(const uint4*)&sbuf[row_l * CS + chunk * 8];
                *(uint4*)&QS[(size_t)gr * QS_W + cbase + chunk * 8] = val;
            }
        }
    } else if (n0 < 512) {
        // k (256..511) -> K16 fp16 compact rows
        int cbase = n0 - 256;
        #pragma unroll
        for (int g = 0; g < 8; g++) {
            int row_l = g * 16 + rbase;
            int gr = row0 + row_l;
            if (gr < M) {
                uint4 val = *(const uint4*)&sbuf[row_l * CS + chunk * 8];
                *(uint4*)&K16[(size_t)gr * K_W + cbase + chunk * 8] = val;
            }
        }
    } else {
        // v (512..767) -> V8 fp8 e4m3 compact rows
        int cbase = n0 - 512;
        #pragma unroll
        for (int g = 0; g < 8; g++) {
            int row_l = g * 16 + rbase;
            int gr = row0 + row_l;
            if (gr < M) {
                uint4 val = *(const uint4*)&sbuf[row_l * CS + chunk * 8];
                uint2 enc = enc8(val);
                *(uint2*)&V8[(size_t)gr * KV_W + cbase + chunk * 8] = enc;
            }
        }
    }
}

// ---------------- attention (fp16 q/k/s, fp8 v): one wave per node, half-wave split ----------------
// BIT-IDENTICAL to round 8 (best verified: 66.2us, absmax 0.1015625, at gather-service floor).

__global__ __launch_bounds__(256) void k_attn_mix(const unsigned short* __restrict__ qs,
                                                  const unsigned short* __restrict__ k16,
                                                  const unsigned char* __restrict__ v8,
                                                  const int* __restrict__ rowptr,
                                                  const int* __restrict__ deg,
                                                  const int* __restrict__ csr_src,
                                                  float* __restrict__ out)
{
    int wave = threadIdx.x >> 6;
    int lane = threadIdx.x & 63;
    int node = blockIdx.x * 4 + wave;
    if (node >= NODES) return;
    int half = lane >> 5;
    int lh = lane & 31;

    const unsigned short* qrow = qs + (size_t)node * QS_W;
    uint4 qv = *(const uint4*)&qrow[lh * 8];   // stays packed; fdot2 consumes half2 directly

    int start = rowptr[node];
    int cnt = deg[node];

    float m = -INFINITY, L = 0.f;
    float acc[8] = {0.f, 0.f, 0.f, 0.f, 0.f, 0.f, 0.f, 0.f};

    if (cnt > 0) {
        int clast = cnt - 1;
        #define CPOS(p) (start + (((2 * (p) + half) > clast) ? clast : (2 * (p) + half)))
        int i0  = csr_src[CPOS(0)];
        int i1  = csr_src[CPOS(1)];
        int ixA = csr_src[CPOS(2)];
        int ixB = csr_src[CPOS(3)];
        uint4 kA, kB;
        uint2 vA, vB;
        kA = *(const uint4*)&k16[(size_t)i0 * K_W + lh * 8];
        vA = *(const uint2*)&v8[(size_t)i0 * KV_W + lh * 8];
        kB = *(const uint4*)&k16[(size_t)i1 * K_W + lh * 8];
        vB = *(const uint2*)&v8[(size_t)i1 * KV_W + lh * 8];
        int npairs = (cnt + 1) >> 1;
        for (int i = 0; i < npairs; i += 2) {
            // ========== sub-iter A: pair i (slot A) ==========
            {
                const unsigned short* pkA = k16 + (size_t)ixA * K_W + lh * 8;
                const unsigned char*  pvA = v8  + (size_t)ixA * KV_W + lh * 8;
                ixA = csr_src[CPOS(i + 4)];              // refill index slot (distance 4)
                float d  = fdot2(u2h2(qv.x), u2h2(kA.x), 0.f);
                d        = fdot2(u2h2(qv.y), u2h2(kA.y), d);
                float d2 = fdot2(u2h2(qv.z), u2h2(kA.z), 0.f);
                d2       = fdot2(u2h2(qv.w), u2h2(kA.w), d2);
                d += d2;
                kA = *(const uint4*)pkA;                 // reload slot (pair i+2)
                d = dpp_xor_add<0xB1>(d);                // xor1
                d = dpp_xor_add<0x4E>(d);                // xor2
                d = dpp_xor_add<0x141>(d);               // xor4 (row_half_mirror)
                float al = d * 0.125f;                   // / sqrt(64)
                bool valid = (2 * i + half) < cnt;
                if (valid) {
                    if (__any(al > m + 8.f)) {           // defer-max: rescale rarely
                        float nm = fmaxf(m, al);
                        float sc = __expf(m - nm);       // exp(-inf)=0 on first edge
                        L *= sc;
                        #pragma unroll
                        for (int t = 0; t < 8; t++) acc[t] *= sc;
                        m = nm;
                    }
                    float p = __expf(al - m);            // bounded by e^8
                    L += p;
                    float vf[8];
                    dec8(vA, vf);
                    #pragma unroll
                    for (int t = 0; t < 8; t++) acc[t] = fmaf(p, vf[t], acc[t]);
                }
                vA = *(const uint2*)pvA;                 // reload slot (pair i+2)
            }
            // ========== sub-iter B: pair i+1 (slot B) ==========
            {
                const unsigned short* pkB = k16 + (size_t)ixB * K_W + lh * 8;
                const unsigned char*  pvB = v8  + (size_t)ixB * KV_W + lh * 8;
                ixB = csr_src[CPOS(i + 5)];              // refill index slot (distance 4)
                float d  = fdot2(u2h2(qv.x), u2h2(kB.x), 0.f);
                d        = fdot2(u2h2(qv.y), u2h2(kB.y), d);
                float d2 = fdot2(u2h2(qv.z), u2h2(kB.z), 0.f);
                d2       = fdot2(u2h2(qv.w), u2h2(kB.w), d2);
                d += d2;
                kB = *(const uint4*)pkB;                 // reload slot (pair i+3)
                d = dpp_xor_add<0xB1>(d);
                d = dpp_xor_add<0x4E>(d);
                d = dpp_xor_add<0x141>(d);
                float al = d * 0.125f;
                bool valid = (2 * (i + 1) + half) < cnt;
                if (valid) {
                    if (__any(al > m + 8.f)) {
                        float nm = fmaxf(m, al);
                        float sc = __expf(m - nm);
                        L *= sc;
                        #pragma unroll
                        for (int t = 0; t < 8; t++) acc[t] *= sc;
                        m = nm;
                    }
                    float p = __expf(al - m);
                    L += p;
                    float vf[8];
                    dec8(vB, vf);
                    #pragma unroll
                    for (int t = 0; t < 8; t++) acc[t] = fmaf(p, vf[t], acc[t]);
                }
                vB = *(const uint2*)pvB;                 // reload slot (pair i+3)
            }
        }
        #undef CPOS
    }

    // ---- merge the two half-wave softmax states
    float mo = __shfl_xor(m, 32, 64);
    float Lo = __shfl_xor(L, 32, 64);
    float nm = fmaxf(m, mo);
    float scs = (L  > 0.f) ? __expf(m  - nm) : 0.f;   // guards cnt==0 / single-edge
    float sco = (Lo > 0.f) ? __expf(mo - nm) : 0.f;
    float Lt = fmaf(L, scs, Lo * sco);
    float inv = (Lt > 0.f) ? 1.f / Lt : 0.f;
    float t0 = fmaf(acc[0], scs, __shfl_xor(acc[0], 32, 64) * sco);
    float t1 = fmaf(acc[1], scs, __shfl_xor(acc[1], 32, 64) * sco);
    float t2 = fmaf(acc[2], scs, __shfl_xor(acc[2], 32, 64) * sco);
    float t3 = fmaf(acc[3], scs, __shfl_xor(acc[3], 32, 64) * sco);
    float t4 = fmaf(acc[4], scs, __shfl_xor(acc[4], 32, 64) * sco);
    float t5 = fmaf(acc[5], scs, __shfl_xor(acc[5], 32, 64) * sco);
    float t6 = fmaf(acc[6], scs, __shfl_xor(acc[6], 32, 64) * sco);
    float t7 = fmaf(acc[7], scs, __shfl_xor(acc[7], 32, 64) * sco);
    // lane writes 4 of its 8 channels: lo half -> ch 8lh+0..3, hi half -> ch 8lh+4..7
    float w0 = half ? t4 : t0;
    float w1 = half ? t5 : t1;
    float w2 = half ? t6 : t2;
    float w3 = half ? t7 : t3;
    ushort4 sv = *(const ushort4*)&qrow[256 + lh * 8 + half * 4];   // s block
    float4 o;
    o.x = fmaf(w0, inv, h2f(sv.x));
    o.y = fmaf(w1, inv, h2f(sv.y));
    o.z = fmaf(w2, inv, h2f(sv.z));
    o.w = fmaf(w3, inv, h2f(sv.w));
    *(float4*)&out[(size_t)node * OUT_W + lh * 8 + half * 4] = o;
}

// ---------------- BatchNorm ----------------

__global__ __launch_bounds__(256) void k_bnstats(const float* __restrict__ h,
                                                 float* __restrict__ sum, float* __restrict__ sumsq) {
    int col = threadIdx.x;
    int r0 = blockIdx.x * 64;
    int r1 = min(r0 + 64, NODES);
    float s = 0.f, s2 = 0.f;
    for (int r = r0; r < r1; r++) {
        float v = h[(size_t)r * OUT_W + col];
        s += v; s2 += v * v;
    }
    atomicAdd(&sum[col], s);
    atomicAdd(&sumsq[col], s2);
}

__device__ __forceinline__ float4 bn_scale4(const float* sum, const float* sumsq,
                                            const float* g, const float* be,
                                            int col, float4* shift) {
    float4 s  = *(const float4*)&sum[col];
    float4 s2 = *(const float4*)&sumsq[col];
    float4 gv = *(const float4*)&g[col];
    float4 bv = *(const float4*)&be[col];
    const float invN = 1.0f / NODES;
    float4 sc, sh;
    float mean, var;
    mean = s.x * invN; var = fmaxf(s2.x * invN - mean * mean, 0.f);
    sc.x = gv.x * rsqrtf(var + BN_EPS); sh.x = bv.x - mean * sc.x;
    mean = s.y * invN; var = fmaxf(s2.y * invN - mean * mean, 0.f);
    sc.y = gv.y * rsqrtf(var + BN_EPS); sh.y = bv.y - mean * sc.y;
    mean = s.z * invN; var = fmaxf(s2.z * invN - mean * mean, 0.f);
    sc.z = gv.z * rsqrtf(var + BN_EPS); sh.z = bv.z - mean * sc.z;
    mean = s.w * invN; var = fmaxf(s2.w * invN - mean * mean, 0.f);
    sc.w = gv.w * rsqrtf(var + BN_EPS); sh.w = bv.w - mean * sc.w;
    *shift = sh;
    return sc;
}

// layer-1 apply: fp32 in -> fp16 out (feeds GEMM2)
__global__ __launch_bounds__(256) void k_bnapply_f16(const float* __restrict__ h,
                                                     const float* __restrict__ sum,
                                                     const float* __restrict__ sumsq,
                                                     const float* __restrict__ g,
                                                     const float* __restrict__ be,
                                                     unsigned short* __restrict__ out) {
    int idx = blockIdx.x * 256 + threadIdx.x;
    int base = idx * 4;
    int col = base & (OUT_W - 1);
    float4 sh;
    float4 sc = bn_scale4(sum, sumsq, g, be, col, &sh);
    float4 v = *(const float4*)&h[base];
    float4 o;
    o.x = v.x * sc.x + sh.x; o.x = (o.x >= 0.f) ? o.x : 0.1f * o.x;
    o.y = v.y * sc.y + sh.y; o.y = (o.y >= 0.f) ? o.y : 0.1f * o.y;
    o.z = v.z * sc.z + sh.z; o.z = (o.z >= 0.f) ? o.z : 0.1f * o.z;
    o.w = v.w * sc.w + sh.w; o.w = (o.w >= 0.f) ? o.w : 0.1f * o.w;
    ushort4 u; u.x = f2h(o.x); u.y = f2h(o.y); u.z = f2h(o.z); u.w = f2h(o.w);
    *(ushort4*)&out[base] = u;
}

// layer-2 apply: fp32 in -> fp32 out (final output)
__global__ __launch_bounds__(256) void k_bnapply(const float* __restrict__ h,
                                                 const float* __restrict__ sum,
                                                 const float* __restrict__ sumsq,
                                                 const float* __restrict__ g,
                                                 const float* __restrict__ be,
                                                 float* __restrict__ out) {
    int idx = blockIdx.x * 256 + threadIdx.x;
    int base = idx * 4;
    int col = base & (OUT_W - 1);
    float4 sh;
    float4 sc = bn_scale4(sum, sumsq, g, be, col, &sh);
    float4 v = *(const float4*)&h[base];
    float4 o;
    o.x = v.x * sc.x + sh.x; o.x = (o.x >= 0.f) ? o.x : 0.1f * o.x;
    o.y = v.y * sc.y + sh.y; o.y = (o.y >= 0.f) ? o.y : 0.1f * o.y;
    o.z = v.z * sc.z + sh.z; o.z = (o.z >= 0.f) ? o.z : 0.1f * o.z;
    o.w = v.w * sc.w + sh.w; o.w = (o.w >= 0.f) ? o.w : 0.1f * o.w;
    *(float4*)&out[base] = o;
}

// ---------------- launch ----------------
// Dispatch chain reduced 19 -> 13 ops (this round's single variable; hot kernels untouched):
//   k_init (was 2 memsets) -> k_castAW (was castA+castW2t) -> k_count -> k_scan1 (was
//   blocksum+scanb+localscan) -> k_fill -> [gemm, attn, stats, apply] x 2.

extern "C" void kernel_launch(void* const* d_in, const int* in_sizes, int n_in,
                              void* d_out, int out_size, void* d_ws, size_t ws_size,
                              hipStream_t stream) {
    const float* x  = (const float*)d_in[0];
    const int*   ei = (const int*)d_in[1];
    const float* w1[4] = {(const float*)d_in[2], (const float*)d_in[4], (const float*)d_in[6], (const float*)d_in[8]};
    const float* b1[4] = {(const float*)d_in[3], (const float*)d_in[5], (const float*)d_in[7], (const float*)d_in[9]};
    const float* g1  = (const float*)d_in[10];
    const float* be1 = (const float*)d_in[11];
    const float* w2[4] = {(const float*)d_in[12], (const float*)d_in[14], (const float*)d_in[16], (const float*)d_in[18]};
    const float* b2[4] = {(const float*)d_in[13], (const float*)d_in[15], (const float*)d_in[17], (const float*)d_in[19]};
    const float* g2  = (const float*)d_in[20];
    const float* be2 = (const float*)d_in[21];

    char* ws = (char*)d_ws;
    unsigned short* qsb    = (unsigned short*)(ws);                 // 30,720,000 (fp16 [q|s])
    unsigned short* k16b   = (unsigned short*)(ws + 30720000);      // 15,360,000 (fp16 k)
    unsigned char*  v8b    = (unsigned char*)(ws + 46080000);       //  7,680,000 (fp8 v)
    float*          h1     = (float*)(ws + 53760000);               // 30,720,000
    unsigned short* abuf   = (unsigned short*)(ws + 84480000);      // 15,360,000 (fp16 GEMM input)
    unsigned short* wt1    = (unsigned short*)(ws + 99840000);      // 524,288
    unsigned short* wt2    = (unsigned short*)(ws + 100364288);     // 524,288
    float*          b1f    = (float*)(ws + 100888576);              // 4,096
    float*          b2f    = (float*)(ws + 100892672);              // 4,096
    int*            deg    = (int*)  (ws + 100896768);              // 120,000
    int*            rowptr = (int*)  (ws + 101016768);              // 120,000
    int*            cursor = (int*)  (ws + 101136768);              // 120,000
    int*            csr    = (int*)  (ws + 101256768);              // 2,400,000
    float*          sum1   = (float*)(ws + 103657792);              // 4 x 1024 B contiguous
    float*          sq1    = (float*)(ws + 103658816);
    float*          sum2   = (float*)(ws + 103659840);
    float*          sq2    = (float*)(ws + 103660864);

    const int EB = (EDGES + 255) / 256;       // 2344
    const int NB = (NODES + 255) / 256;       // 118

    k_init   <<<NB, 256, 0, stream>>>(deg, sum1);      // deg + all 4 BN sum arrays
    k_castAW <<<128 + (NODES * 256 / 8 + 255) / 256, 256, 0, stream>>>(
        x, abuf,
        w1[0], w1[1], w1[2], w1[3], b1[0], b1[1], b1[2], b1[3],
        w2[0], w2[1], w2[2], w2[3], b2[0], b2[1], b2[2], b2[3],
        wt1, b1f, wt2, b2f);

    // CSR (shared by both layers)
    k_count <<<EB, 256, 0, stream>>>(ei, deg);
    k_scan1 <<<1, 1024, 0, stream>>>(deg, rowptr, cursor);
    k_fill  <<<EB, 256, 0, stream>>>(ei, cursor, csr);

    const int GB = 235 * 8;                   // 1880 blocks, XCD-swizzled in-kernel
    const int ANB = NODES / 4;                // 7500
    const int APB = (NODES * OUT_W / 4) / 256;// 7500
    const int SNB = (NODES + 63) / 64;        // 469

    // layer 1
    k_gemm_f16   <<<GB, 256, 0, stream>>>(abuf, wt1, b1f, qsb, k16b, v8b, NODES);
    k_attn_mix   <<<ANB, 256, 0, stream>>>(qsb, k16b, v8b, rowptr, deg, csr, h1);
    k_bnstats    <<<SNB, 256, 0, stream>>>(h1, sum1, sq1);
    k_bnapply_f16<<<APB, 256, 0, stream>>>(h1, sum1, sq1, g1, be1, abuf);

    // layer 2
    k_gemm_f16   <<<GB, 256, 0, stream>>>(abuf, wt2, b2f, qsb, k16b, v8b, NODES);
    k_attn_mix   <<<ANB, 256, 0, stream>>>(qsb, k16b, v8b, rowptr, deg, csr, h1);
    k_bnstats    <<<SNB, 256, 0, stream>>>(h1, sum2, sq2);
    k_bnapply    <<<APB, 256, 0, stream>>>(h1, sum2, sq2, g2, be2, (float*)d_out);
}

// Round 13
// 452.689 us; speedup vs baseline: 1.1098x; 1.1098x over previous
//
#include <hip/hip_runtime.h>
#include <math.h>

#define NODES 30000
#define EDGES 600000
#define QS_W 512     // fp16 row: [q 256 | s 256]
#define K_W 256      // fp16 k row: 256 ushorts (512 B)
#define KV_W 256     // fp8 v row: 256 bytes
#define OUT_W 256
#define BN_EPS 1e-5f

typedef _Float16 f16x8 __attribute__((ext_vector_type(8)));
typedef _Float16 half2t __attribute__((ext_vector_type(2)));
typedef float f32x2 __attribute__((ext_vector_type(2)));
typedef __attribute__((ext_vector_type(4))) float f32x4;

__device__ __forceinline__ unsigned short f2h(float f) {
    union { _Float16 h; unsigned short u; } v;
    v.h = (_Float16)f;                      // v_cvt_f16_f32 (RNE)
    return v.u;
}
__device__ __forceinline__ float h2f(unsigned short u) {
    union { unsigned short u; _Float16 h; } v; v.u = u;
    return (float)v.h;
}
__device__ __forceinline__ half2t u2h2(unsigned int u) {
    union { unsigned int u; half2t h; } v; v.u = u;
    return v.h;
}

__device__ __forceinline__ float fdot2(half2t a, half2t b, float c) {
#if __has_builtin(__builtin_amdgcn_fdot2)
    return __builtin_amdgcn_fdot2(a, b, c, false);
#else
    return fmaf((float)a.x, (float)b.x, fmaf((float)a.y, (float)b.y, c));
#endif
}

// ---- OCP e4m3 pack/unpack (HW cvt when available; exact bit-math fallback) ----
// fallback math: e4m3 bits<<7 reinterpreted as fp16 = value * 2^-8 (exact incl. denorms)

__device__ __forceinline__ void dec8(uint2 w, float* f) {
#if __has_builtin(__builtin_amdgcn_cvt_pk_f32_fp8)
    f32x2 a = __builtin_amdgcn_cvt_pk_f32_fp8((int)w.x, false);
    f32x2 b = __builtin_amdgcn_cvt_pk_f32_fp8((int)w.x, true);
    f32x2 c = __builtin_amdgcn_cvt_pk_f32_fp8((int)w.y, false);
    f32x2 d = __builtin_amdgcn_cvt_pk_f32_fp8((int)w.y, true);
    f[0] = a.x; f[1] = a.y; f[2] = b.x; f[3] = b.y;
    f[4] = c.x; f[5] = c.y; f[6] = d.x; f[7] = d.y;
#else
    #pragma unroll
    for (int j = 0; j < 8; j++) {
        unsigned int byte = ((j < 4 ? w.x : w.y) >> ((j & 3) * 8)) & 0xFF;
        unsigned short h = (unsigned short)(((byte & 0x80u) << 8) | ((byte & 0x7Fu) << 7));
        f[j] = h2f(h) * 256.0f;
    }
#endif
}

__device__ __forceinline__ uint2 enc8(uint4 w) {
    float f[8];
    f[0] = h2f((unsigned short)(w.x & 0xffff)); f[1] = h2f((unsigned short)(w.x >> 16));
    f[2] = h2f((unsigned short)(w.y & 0xffff)); f[3] = h2f((unsigned short)(w.y >> 16));
    f[4] = h2f((unsigned short)(w.z & 0xffff)); f[5] = h2f((unsigned short)(w.z >> 16));
    f[6] = h2f((unsigned short)(w.w & 0xffff)); f[7] = h2f((unsigned short)(w.w >> 16));
    uint2 r;
#if __has_builtin(__builtin_amdgcn_cvt_pk_fp8_f32)
    int lo = 0, hi = 0;
    lo = __builtin_amdgcn_cvt_pk_fp8_f32(f[0], f[1], lo, false);
    lo = __builtin_amdgcn_cvt_pk_fp8_f32(f[2], f[3], lo, true);
    hi = __builtin_amdgcn_cvt_pk_fp8_f32(f[4], f[5], hi, false);
    hi = __builtin_amdgcn_cvt_pk_fp8_f32(f[6], f[7], hi, true);
    r.x = (unsigned)lo; r.y = (unsigned)hi;
#else
    unsigned b[8];
    #pragma unroll
    for (int j = 0; j < 8; j++) {
        unsigned short hb = f2h(f[j] * 0.00390625f);   // *2^-8
        unsigned m = hb & 0x7fffu;
        unsigned rr = m + 0x3Fu + ((m >> 7) & 1u);     // RNE on dropped 7 bits
        b[j] = ((hb >> 8) & 0x80u) | ((rr >> 7) & 0x7Fu);
    }
    r.x = b[0] | (b[1] << 8) | (b[2] << 16) | (b[3] << 24);
    r.y = b[4] | (b[5] << 8) | (b[6] << 16) | (b[7] << 24);
#endif
    return r;
}

// butterfly add via DPP (VALU pipe). 0xB1=xor1, 0x4E=xor2, 0x141=row_half_mirror(^4 after folds)
template<int CTRL>
__device__ __forceinline__ float dpp_xor_add(float x) {
    int xi = __builtin_bit_cast(int, x);
    int yi = __builtin_amdgcn_mov_dpp(xi, CTRL, 0xF, 0xF, true);
    return x + __builtin_bit_cast(float, yi);
}

typedef const __attribute__((address_space(1))) void* gas_p;
typedef __attribute__((address_space(3))) void* las_p;
__device__ __forceinline__ void gload_lds16(const void* g, void* l) {
    __builtin_amdgcn_global_load_lds((gas_p)g, (las_p)l, 16, 0, 0);
}

// ---------------- init: zero deg + BN sum arrays (replaces 2 memset dispatches) ----------------

__global__ __launch_bounds__(256) void k_init(int* __restrict__ deg, float* __restrict__ sums) {
    int i = blockIdx.x * 256 + threadIdx.x;
    if (i < NODES) deg[i] = 0;
    if (blockIdx.x == 0) {
        // 1024 floats (sum1|sq1|sum2|sq2 contiguous), 4 per thread
        #pragma unroll
        for (int j = 0; j < 4; j++) sums[threadIdx.x * 4 + j] = 0.f;
    }
}

// ---------------- CSR build (parallel 3-kernel scan restored from r11; r12's single-block
// k_scan1 serialized the GPU behind one CU and cost ~+47us) ----------------

__global__ __launch_bounds__(256) void k_count(const int* __restrict__ ei, int* __restrict__ deg) {
    int e = blockIdx.x * 256 + threadIdx.x;
    if (e < EDGES) atomicAdd(&deg[ei[EDGES + e]], 1);   // dst row
}

__global__ __launch_bounds__(256) void k_blocksum(const int* __restrict__ deg, int* __restrict__ bsum) {
    __shared__ int sh[256];
    int i = blockIdx.x * 256 + threadIdx.x;
    sh[threadIdx.x] = (i < NODES) ? deg[i] : 0;
    __syncthreads();
    for (int off = 128; off > 0; off >>= 1) {
        if (threadIdx.x < off) sh[threadIdx.x] += sh[threadIdx.x + off];
        __syncthreads();
    }
    if (threadIdx.x == 0) bsum[blockIdx.x] = sh[0];
}

__global__ __launch_bounds__(128) void k_scanb(const int* __restrict__ bsum, int* __restrict__ bbase, int nb) {
    __shared__ int sh[128];
    int t = threadIdx.x;
    int v = (t < nb) ? bsum[t] : 0;
    sh[t] = v;
    __syncthreads();
    for (int off = 1; off < 128; off <<= 1) {
        int add = (t >= off) ? sh[t - off] : 0;
        __syncthreads();
        sh[t] += add;
        __syncthreads();
    }
    if (t < nb) bbase[t] = sh[t] - v;   // exclusive
}

__global__ __launch_bounds__(256) void k_localscan(const int* __restrict__ deg, const int* __restrict__ bbase,
                                                   int* __restrict__ rowptr, int* __restrict__ cursor) {
    __shared__ int sh[256];
    int i = blockIdx.x * 256 + threadIdx.x;
    int v = (i < NODES) ? deg[i] : 0;
    sh[threadIdx.x] = v;
    __syncthreads();
    for (int off = 1; off < 256; off <<= 1) {
        int add = (threadIdx.x >= off) ? sh[threadIdx.x - off] : 0;
        __syncthreads();
        sh[threadIdx.x] += add;
        __syncthreads();
    }
    if (i < NODES) {
        int p = bbase[blockIdx.x] + sh[threadIdx.x] - v;  // exclusive
        rowptr[i] = p;
        cursor[i] = p;
    }
}

__global__ __launch_bounds__(256) void k_fill(const int* __restrict__ ei, int* __restrict__ cursor,
                                              int* __restrict__ csr_src) {
    int e = blockIdx.x * 256 + threadIdx.x;
    if (e < EDGES) {
        int s = ei[e];
        int d = ei[EDGES + e];
        int slot = atomicAdd(&cursor[d], 1);
        csr_src[slot] = s;
    }
}

// ---------------- fused cast: blocks [0,128) = W transpose-cast; rest = A cast ----------------
// W path: values bit-identical to the original k_castW2 (coalesced via 64x64 LDS tile).
// A path: fp32 x -> fp16 abuf, 8 elems/thread.

__global__ __launch_bounds__(256) void k_castAW(
    const float* __restrict__ x, unsigned short* __restrict__ abuf,
    const float* __restrict__ Wa0, const float* __restrict__ Wa1,
    const float* __restrict__ Wa2, const float* __restrict__ Wa3,
    const float* __restrict__ Ba0, const float* __restrict__ Ba1,
    const float* __restrict__ Ba2, const float* __restrict__ Ba3,
    const float* __restrict__ Wb0, const float* __restrict__ Wb1,
    const float* __restrict__ Wb2, const float* __restrict__ Wb3,
    const float* __restrict__ Bb0, const float* __restrict__ Bb1,
    const float* __restrict__ Bb2, const float* __restrict__ Bb3,
    unsigned short* __restrict__ Wt1, float* __restrict__ bf1,
    unsigned short* __restrict__ Wt2, float* __restrict__ bf2)
{
    __shared__ float tile[64][65];
    int b = blockIdx.x;
    if (b >= 128) {
        // ---- A cast: item index over NODES*256/8 = 960000
        int i = (b - 128) * 256 + threadIdx.x;
        if (i >= NODES * 256 / 8) return;
        const float4* p = (const float4*)(x + (size_t)i * 8);
        float4 v0 = p[0], v1 = p[1];
        ushort4 o0, o1;
        o0.x = f2h(v0.x); o0.y = f2h(v0.y); o0.z = f2h(v0.z); o0.w = f2h(v0.w);
        o1.x = f2h(v1.x); o1.y = f2h(v1.y); o1.z = f2h(v1.z); o1.w = f2h(v1.w);
        ushort4* q = (ushort4*)(abuf + (size_t)i * 8);
        q[0] = o0; q[1] = o1;
        return;
    }
    // ---- W transpose-cast
    int layer = b >> 6;
    int wsel = (b >> 4) & 3;
    int kt = (b >> 2) & 3;   // k-row tile of W (64 rows)
    int ct = b & 3;          // col tile of W (64 cols)
    const float* W; const float* Bv;
    if (layer == 0) {
        W  = (wsel == 0) ? Wa0 : (wsel == 1) ? Wa1 : (wsel == 2) ? Wa2 : Wa3;
        Bv = (wsel == 0) ? Ba0 : (wsel == 1) ? Ba1 : (wsel == 2) ? Ba2 : Ba3;
    } else {
        W  = (wsel == 0) ? Wb0 : (wsel == 1) ? Wb1 : (wsel == 2) ? Wb2 : Wb3;
        Bv = (wsel == 0) ? Bb0 : (wsel == 1) ? Bb1 : (wsel == 2) ? Bb2 : Bb3;
    }
    unsigned short* Wt = (layer == 0) ? Wt1 : Wt2;
    float* bfused = (layer == 0) ? bf1 : bf2;

    int t = threadIdx.x;
    int tr = t >> 4;           // 0..15
    int tc4 = (t & 15) * 4;    // 0,4,...,60
    #pragma unroll
    for (int r = 0; r < 64; r += 16) {
        float4 v = *(const float4*)&W[(size_t)(kt * 64 + tr + r) * 256 + ct * 64 + tc4];
        tile[tr + r][tc4 + 0] = v.x;
        tile[tr + r][tc4 + 1] = v.y;
        tile[tr + r][tc4 + 2] = v.z;
        tile[tr + r][tc4 + 3] = v.w;
    }
    __syncthreads();
    #pragma unroll
    for (int r = 0; r < 64; r += 16) {
        int nr = tr + r;                       // col-local of W == row-local of Wt
        ushort4 o;
        o.x = f2h(tile[tc4 + 0][nr]);
        o.y = f2h(tile[tc4 + 1][nr]);
        o.z = f2h(tile[tc4 + 2][nr]);
        o.w = f2h(tile[tc4 + 3][nr]);
        *(ushort4*)&Wt[(size_t)(wsel * 256 + ct * 64 + nr) * 256 + kt * 64 + tc4] = o;
    }
    if (kt == 0 && t < 64) bfused[wsel * 256 + ct * 64 + t] = Bv[ct * 64 + t];
}

// ---------------- fp16 MFMA GEMM; XCD-chunked block swizzle; epilogue: QS/K16/V8 ----------------
// 1880 flat blocks = 235 row x 8 col; xcd = bid%8 owns a contiguous sbid chunk (bijective).

#define CS 136   // padded LDS stride (ushorts) for the 128x128 C tile

__global__ __launch_bounds__(256) void k_gemm_f16(
    const unsigned short* __restrict__ A,
    const unsigned short* __restrict__ Wt,
    const float* __restrict__ bias,
    unsigned short* __restrict__ QS,
    unsigned short* __restrict__ K16,
    unsigned char* __restrict__ V8, int M)
{
    __shared__ unsigned short sbuf[128 * CS];   // 34,816 B; unions staging (32KB) and epilogue
    unsigned short* As = sbuf;                  // 128*64
    unsigned short* Bs = sbuf + 8192;           // 128*64
    int tid = threadIdx.x;
    int lane = tid & 63;
    int wave = tid >> 6;
    int wm = wave & 1, wn = wave >> 1;      // 2x2 waves -> 64x64 each

    // XCD-chunked swizzle: xcd = bid%8 owns sbid range [xcd*235, (xcd+1)*235)
    int bid = blockIdx.x;
    int sbid = (bid & 7) * 235 + (bid >> 3);
    int row0 = (sbid >> 3) * 128;           // row-block   (0..234)
    int n0 = (sbid & 7) * 128;              // col-block in fused 1024-col space

    f32x4 acc[4][4] = {};

    for (int k0 = 0; k0 < 256; k0 += 64) {
        #pragma unroll
        for (int w = 0; w < 4; w++) {
            int c = w * 256 + tid;
            int row = c >> 3;
            int cole = (c & 7) * 8;
            int ar = row0 + row; if (ar >= M) ar = M - 1;
            gload_lds16(&A[(size_t)ar * 256 + k0 + cole], &As[w * 2048 + tid * 8]);
            gload_lds16(&Wt[(size_t)(n0 + row) * 256 + k0 + cole], &Bs[w * 2048 + tid * 8]);
        }
        __syncthreads();
        int rsel = lane & 15;
        int kq = (lane >> 4) * 8;
        #pragma unroll
        for (int kh = 0; kh < 2; kh++) {
            f16x8 af[4], bfr[4];
            #pragma unroll
            for (int t = 0; t < 4; t++) {
                af[t]  = *reinterpret_cast<const f16x8*>(&As[(wm * 64 + t * 16 + rsel) * 64 + kh * 32 + kq]);
                bfr[t] = *reinterpret_cast<const f16x8*>(&Bs[(wn * 64 + t * 16 + rsel) * 64 + kh * 32 + kq]);
            }
            #pragma unroll
            for (int mt = 0; mt < 4; mt++)
                #pragma unroll
                for (int nt = 0; nt < 4; nt++)
                    acc[mt][nt] = __builtin_amdgcn_mfma_f32_16x16x32_f16(af[mt], bfr[nt], acc[mt][nt], 0, 0, 0);
        }
        __syncthreads();
    }

    // epilogue: stage fp16(+bias) tile into padded LDS (C/D map: col=lane&15, row=(lane>>4)*4+reg)
    int crow = (lane >> 4) * 4;
    int ccol = lane & 15;
    #pragma unroll
    for (int mt = 0; mt < 4; mt++) {
        int lrow = wm * 64 + mt * 16 + crow;
        #pragma unroll
        for (int nt = 0; nt < 4; nt++) {
            int lcol = wn * 64 + nt * 16 + ccol;
            float bv = bias[n0 + lcol];
            #pragma unroll
            for (int r = 0; r < 4; r++)
                sbuf[(lrow + r) * CS + lcol] = f2h(acc[mt][nt][r] + bv);
        }
    }
    __syncthreads();
    int chunk = tid & 15;
    int rbase = tid >> 4;
    if (n0 < 256 || n0 >= 768) {
        // q (cols 0..255) or s (768..1023) -> fp16 qs rows [q|s]
        int cbase = (n0 < 256) ? n0 : (n0 - 512);
        #pragma unroll
        for (int g = 0; g < 8; g++) {
            int row_l = g * 16 + rbase;
            int gr = row0 + row_l;
            if (gr < M) {
                uint4 val = *(const uint4*)&sbuf[row_l * CS + chunk * 8];
                *(uint4*)&QS[(size_t)gr * QS_W + cbase + chunk * 8] = val;
            }
        }
    } else if (n0 < 512) {
        // k (256..511) -> K16 fp16 compact rows
        int cbase = n0 - 256;
        #pragma unroll
        for (int g = 0; g < 8; g++) {
            int row_l = g * 16 + rbase;
            int gr = row0 + row_l;
            if (gr < M) {
                uint4 val = *(const uint4*)&sbuf[row_l * CS + chunk * 8];
                *(uint4*)&K16[(size_t)gr * K_W + cbase + chunk * 8] = val;
            }
        }
    } else {
        // v (512..767) -> V8 fp8 e4m3 compact rows
        int cbase = n0 - 512;
        #pragma unroll
        for (int g = 0; g < 8; g++) {
            int row_l = g * 16 + rbase;
            int gr = row0 + row_l;
            if (gr < M) {
                uint4 val = *(const uint4*)&sbuf[row_l * CS + chunk * 8];
                uint2 enc = enc8(val);
                *(uint2*)&V8[(size_t)gr * KV_W + cbase + chunk * 8] = enc;
            }
        }
    }
}

// ---------------- attention (fp16 q/k/s, fp8 v): one wave per node, half-wave split ----------------
// BIT-IDENTICAL to round 8 (best verified: 66.2us, absmax 0.1015625, at gather-service floor).

__global__ __launch_bounds__(256) void k_attn_mix(const unsigned short* __restrict__ qs,
                                                  const unsigned short* __restrict__ k16,
                                                  const unsigned char* __restrict__ v8,
                                                  const int* __restrict__ rowptr,
                                                  const int* __restrict__ deg,
                                                  const int* __restrict__ csr_src,
                                                  float* __restrict__ out)
{
    int wave = threadIdx.x >> 6;
    int lane = threadIdx.x & 63;
    int node = blockIdx.x * 4 + wave;
    if (node >= NODES) return;
    int half = lane >> 5;
    int lh = lane & 31;

    const unsigned short* qrow = qs + (size_t)node * QS_W;
    uint4 qv = *(const uint4*)&qrow[lh * 8];   // stays packed; fdot2 consumes half2 directly

    int start = rowptr[node];
    int cnt = deg[node];

    float m = -INFINITY, L = 0.f;
    float acc[8] = {0.f, 0.f, 0.f, 0.f, 0.f, 0.f, 0.f, 0.f};

    if (cnt > 0) {
        int clast = cnt - 1;
        #define CPOS(p) (start + (((2 * (p) + half) > clast) ? clast : (2 * (p) + half)))
        int i0  = csr_src[CPOS(0)];
        int i1  = csr_src[CPOS(1)];
        int ixA = csr_src[CPOS(2)];
        int ixB = csr_src[CPOS(3)];
        uint4 kA, kB;
        uint2 vA, vB;
        kA = *(const uint4*)&k16[(size_t)i0 * K_W + lh * 8];
        vA = *(const uint2*)&v8[(size_t)i0 * KV_W + lh * 8];
        kB = *(const uint4*)&k16[(size_t)i1 * K_W + lh * 8];
        vB = *(const uint2*)&v8[(size_t)i1 * KV_W + lh * 8];
        int npairs = (cnt + 1) >> 1;
        for (int i = 0; i < npairs; i += 2) {
            // ========== sub-iter A: pair i (slot A) ==========
            {
                const unsigned short* pkA = k16 + (size_t)ixA * K_W + lh * 8;
                const unsigned char*  pvA = v8  + (size_t)ixA * KV_W + lh * 8;
                ixA = csr_src[CPOS(i + 4)];              // refill index slot (distance 4)
                float d  = fdot2(u2h2(qv.x), u2h2(kA.x), 0.f);
                d        = fdot2(u2h2(qv.y), u2h2(kA.y), d);
                float d2 = fdot2(u2h2(qv.z), u2h2(kA.z), 0.f);
                d2       = fdot2(u2h2(qv.w), u2h2(kA.w), d2);
                d += d2;
                kA = *(const uint4*)pkA;                 // reload slot (pair i+2)
                d = dpp_xor_add<0xB1>(d);                // xor1
                d = dpp_xor_add<0x4E>(d);                // xor2
                d = dpp_xor_add<0x141>(d);               // xor4 (row_half_mirror)
                float al = d * 0.125f;                   // / sqrt(64)
                bool valid = (2 * i + half) < cnt;
                if (valid) {
                    if (__any(al > m + 8.f)) {           // defer-max: rescale rarely
                        float nm = fmaxf(m, al);
                        float sc = __expf(m - nm);       // exp(-inf)=0 on first edge
                        L *= sc;
                        #pragma unroll
                        for (int t = 0; t < 8; t++) acc[t] *= sc;
                        m = nm;
                    }
                    float p = __expf(al - m);            // bounded by e^8
                    L += p;
                    float vf[8];
                    dec8(vA, vf);
                    #pragma unroll
                    for (int t = 0; t < 8; t++) acc[t] = fmaf(p, vf[t], acc[t]);
                }
                vA = *(const uint2*)pvA;                 // reload slot (pair i+2)
            }
            // ========== sub-iter B: pair i+1 (slot B) ==========
            {
                const unsigned short* pkB = k16 + (size_t)ixB * K_W + lh * 8;
                const unsigned char*  pvB = v8  + (size_t)ixB * KV_W + lh * 8;
                ixB = csr_src[CPOS(i + 5)];              // refill index slot (distance 4)
                float d  = fdot2(u2h2(qv.x), u2h2(kB.x), 0.f);
                d        = fdot2(u2h2(qv.y), u2h2(kB.y), d);
                float d2 = fdot2(u2h2(qv.z), u2h2(kB.z), 0.f);
                d2       = fdot2(u2h2(qv.w), u2h2(kB.w), d2);
                d += d2;
                kB = *(const uint4*)pkB;                 // reload slot (pair i+3)
                d = dpp_xor_add<0xB1>(d);
                d = dpp_xor_add<0x4E>(d);
                d = dpp_xor_add<0x141>(d);
                float al = d * 0.125f;
                bool valid = (2 * (i + 1) + half) < cnt;
                if (valid) {
                    if (__any(al > m + 8.f)) {
                        float nm = fmaxf(m, al);
                        float sc = __expf(m - nm);
                        L *= sc;
                        #pragma unroll
                        for (int t = 0; t < 8; t++) acc[t] *= sc;
                        m = nm;
                    }
                    float p = __expf(al - m);
                    L += p;
                    float vf[8];
                    dec8(vB, vf);
                    #pragma unroll
                    for (int t = 0; t < 8; t++) acc[t] = fmaf(p, vf[t], acc[t]);
                }
                vB = *(const uint2*)pvB;                 // reload slot (pair i+3)
            }
        }
        #undef CPOS
    }

    // ---- merge the two half-wave softmax states
    float mo = __shfl_xor(m, 32, 64);
    float Lo = __shfl_xor(L, 32, 64);
    float nm = fmaxf(m, mo);
    float scs = (L  > 0.f) ? __expf(m  - nm) : 0.f;   // guards cnt==0 / single-edge
    float sco = (Lo > 0.f) ? __expf(mo - nm) : 0.f;
    float Lt = fmaf(L, scs, Lo * sco);
    float inv = (Lt > 0.f) ? 1.f / Lt : 0.f;
    float t0 = fmaf(acc[0], scs, __shfl_xor(acc[0], 32, 64) * sco);
    float t1 = fmaf(acc[1], scs, __shfl_xor(acc[1], 32, 64) * sco);
    float t2 = fmaf(acc[2], scs, __shfl_xor(acc[2], 32, 64) * sco);
    float t3 = fmaf(acc[3], scs, __shfl_xor(acc[3], 32, 64) * sco);
    float t4 = fmaf(acc[4], scs, __shfl_xor(acc[4], 32, 64) * sco);
    float t5 = fmaf(acc[5], scs, __shfl_xor(acc[5], 32, 64) * sco);
    float t6 = fmaf(acc[6], scs, __shfl_xor(acc[6], 32, 64) * sco);
    float t7 = fmaf(acc[7], scs, __shfl_xor(acc[7], 32, 64) * sco);
    // lane writes 4 of its 8 channels: lo half -> ch 8lh+0..3, hi half -> ch 8lh+4..7
    float w0 = half ? t4 : t0;
    float w1 = half ? t5 : t1;
    float w2 = half ? t6 : t2;
    float w3 = half ? t7 : t3;
    ushort4 sv = *(const ushort4*)&qrow[256 + lh * 8 + half * 4];   // s block
    float4 o;
    o.x = fmaf(w0, inv, h2f(sv.x));
    o.y = fmaf(w1, inv, h2f(sv.y));
    o.z = fmaf(w2, inv, h2f(sv.z));
    o.w = fmaf(w3, inv, h2f(sv.w));
    *(float4*)&out[(size_t)node * OUT_W + lh * 8 + half * 4] = o;
}

// ---------------- BatchNorm ----------------

__global__ __launch_bounds__(256) void k_bnstats(const float* __restrict__ h,
                                                 float* __restrict__ sum, float* __restrict__ sumsq) {
    int col = threadIdx.x;
    int r0 = blockIdx.x * 64;
    int r1 = min(r0 + 64, NODES);
    float s = 0.f, s2 = 0.f;
    for (int r = r0; r < r1; r++) {
        float v = h[(size_t)r * OUT_W + col];
        s += v; s2 += v * v;
    }
    atomicAdd(&sum[col], s);
    atomicAdd(&sumsq[col], s2);
}

__device__ __forceinline__ float4 bn_scale4(const float* sum, const float* sumsq,
                                            const float* g, const float* be,
                                            int col, float4* shift) {
    float4 s  = *(const float4*)&sum[col];
    float4 s2 = *(const float4*)&sumsq[col];
    float4 gv = *(const float4*)&g[col];
    float4 bv = *(const float4*)&be[col];
    const float invN = 1.0f / NODES;
    float4 sc, sh;
    float mean, var;
    mean = s.x * invN; var = fmaxf(s2.x * invN - mean * mean, 0.f);
    sc.x = gv.x * rsqrtf(var + BN_EPS); sh.x = bv.x - mean * sc.x;
    mean = s.y * invN; var = fmaxf(s2.y * invN - mean * mean, 0.f);
    sc.y = gv.y * rsqrtf(var + BN_EPS); sh.y = bv.y - mean * sc.y;
    mean = s.z * invN; var = fmaxf(s2.z * invN - mean * mean, 0.f);
    sc.z = gv.z * rsqrtf(var + BN_EPS); sh.z = bv.z - mean * sc.z;
    mean = s.w * invN; var = fmaxf(s2.w * invN - mean * mean, 0.f);
    sc.w = gv.w * rsqrtf(var + BN_EPS); sh.w = bv.w - mean * sc.w;
    *shift = sh;
    return sc;
}

// layer-1 apply: fp32 in -> fp16 out (feeds GEMM2)
__global__ __launch_bounds__(256) void k_bnapply_f16(const float* __restrict__ h,
                                                     const float* __restrict__ sum,
                                                     const float* __restrict__ sumsq,
                                                     const float* __restrict__ g,
                                                     const float* __restrict__ be,
                                                     unsigned short* __restrict__ out) {
    int idx = blockIdx.x * 256 + threadIdx.x;
    int base = idx * 4;
    int col = base & (OUT_W - 1);
    float4 sh;
    float4 sc = bn_scale4(sum, sumsq, g, be, col, &sh);
    float4 v = *(const float4*)&h[base];
    float4 o;
    o.x = v.x * sc.x + sh.x; o.x = (o.x >= 0.f) ? o.x : 0.1f * o.x;
    o.y = v.y * sc.y + sh.y; o.y = (o.y >= 0.f) ? o.y : 0.1f * o.y;
    o.z = v.z * sc.z + sh.z; o.z = (o.z >= 0.f) ? o.z : 0.1f * o.z;
    o.w = v.w * sc.w + sh.w; o.w = (o.w >= 0.f) ? o.w : 0.1f * o.w;
    ushort4 u; u.x = f2h(o.x); u.y = f2h(o.y); u.z = f2h(o.z); u.w = f2h(o.w);
    *(ushort4*)&out[base] = u;
}

// layer-2 apply: fp32 in -> fp32 out (final output)
__global__ __launch_bounds__(256) void k_bnapply(const float* __restrict__ h,
                                                 const float* __restrict__ sum,
                                                 const float* __restrict__ sumsq,
                                                 const float* __restrict__ g,
                                                 const float* __restrict__ be,
                                                 float* __restrict__ out) {
    int idx = blockIdx.x * 256 + threadIdx.x;
    int base = idx * 4;
    int col = base & (OUT_W - 1);
    float4 sh;
    float4 sc = bn_scale4(sum, sumsq, g, be, col, &sh);
    float4 v = *(const float4*)&h[base];
    float4 o;
    o.x = v.x * sc.x + sh.x; o.x = (o.x >= 0.f) ? o.x : 0.1f * o.x;
    o.y = v.y * sc.y + sh.y; o.y = (o.y >= 0.f) ? o.y : 0.1f * o.y;
    o.z = v.z * sc.z + sh.z; o.z = (o.z >= 0.f) ? o.z : 0.1f * o.z;
    o.w = v.w * sc.w + sh.w; o.w = (o.w >= 0.f) ? o.w : 0.1f * o.w;
    *(float4*)&out[base] = o;
}

// ---------------- launch ----------------
// r13 = r11 structure with only the SAFE fusions kept (k_init for 2 memsets, k_castAW for
// castA+castW2t); the r12 single-block k_scan1 is REVERTED to the parallel 3-kernel scan.

extern "C" void kernel_launch(void* const* d_in, const int* in_sizes, int n_in,
                              void* d_out, int out_size, void* d_ws, size_t ws_size,
                              hipStream_t stream) {
    const float* x  = (const float*)d_in[0];
    const int*   ei = (const int*)d_in[1];
    const float* w1[4] = {(const float*)d_in[2], (const float*)d_in[4], (const float*)d_in[6], (const float*)d_in[8]};
    const float* b1[4] = {(const float*)d_in[3], (const float*)d_in[5], (const float*)d_in[7], (const float*)d_in[9]};
    const float* g1  = (const float*)d_in[10];
    const float* be1 = (const float*)d_in[11];
    const float* w2[4] = {(const float*)d_in[12], (const float*)d_in[14], (const float*)d_in[16], (const float*)d_in[18]};
    const float* b2[4] = {(const float*)d_in[13], (const float*)d_in[15], (const float*)d_in[17], (const float*)d_in[19]};
    const float* g2  = (const float*)d_in[20];
    const float* be2 = (const float*)d_in[21];

    char* ws = (char*)d_ws;
    unsigned short* qsb    = (unsigned short*)(ws);                 // 30,720,000 (fp16 [q|s])
    unsigned short* k16b   = (unsigned short*)(ws + 30720000);      // 15,360,000 (fp16 k)
    unsigned char*  v8b    = (unsigned char*)(ws + 46080000);       //  7,680,000 (fp8 v)
    float*          h1     = (float*)(ws + 53760000);               // 30,720,000
    unsigned short* abuf   = (unsigned short*)(ws + 84480000);      // 15,360,000 (fp16 GEMM input)
    unsigned short* wt1    = (unsigned short*)(ws + 99840000);      // 524,288
    unsigned short* wt2    = (unsigned short*)(ws + 100364288);     // 524,288
    float*          b1f    = (float*)(ws + 100888576);              // 4,096
    float*          b2f    = (float*)(ws + 100892672);              // 4,096
    int*            deg    = (int*)  (ws + 100896768);              // 120,000
    int*            rowptr = (int*)  (ws + 101016768);              // 120,000
    int*            cursor = (int*)  (ws + 101136768);              // 120,000
    int*            csr    = (int*)  (ws + 101256768);              // 2,400,000
    int*            bsum   = (int*)  (ws + 103656768);              // 512
    int*            bbase  = (int*)  (ws + 103657280);              // 512
    float*          sum1   = (float*)(ws + 103657792);              // 4 x 1024 B contiguous
    float*          sq1    = (float*)(ws + 103658816);
    float*          sum2   = (float*)(ws + 103659840);
    float*          sq2    = (float*)(ws + 103660864);

    const int EB = (EDGES + 255) / 256;       // 2344
    const int NB = (NODES + 255) / 256;       // 118

    k_init   <<<NB, 256, 0, stream>>>(deg, sum1);      // deg + all 4 BN sum arrays
    k_castAW <<<128 + (NODES * 256 / 8 + 255) / 256, 256, 0, stream>>>(
        x, abuf,
        w1[0], w1[1], w1[2], w1[3], b1[0], b1[1], b1[2], b1[3],
        w2[0], w2[1], w2[2], w2[3], b2[0], b2[1], b2[2], b2[3],
        wt1, b1f, wt2, b2f);

    // CSR (shared by both layers) — parallel scan chain
    k_count    <<<EB, 256, 0, stream>>>(ei, deg);
    k_blocksum <<<NB, 256, 0, stream>>>(deg, bsum);
    k_scanb    <<<1, 128, 0, stream>>>(bsum, bbase, NB);
    k_localscan<<<NB, 256, 0, stream>>>(deg, bbase, rowptr, cursor);
    k_fill     <<<EB, 256, 0, stream>>>(ei, cursor, csr);

    const int GB = 235 * 8;                   // 1880 blocks, XCD-swizzled in-kernel
    const int ANB = NODES / 4;                // 7500
    const int APB = (NODES * OUT_W / 4) / 256;// 7500
    const int SNB = (NODES + 63) / 64;        // 469

    // layer 1
    k_gemm_f16   <<<GB, 256, 0, stream>>>(abuf, wt1, b1f, qsb, k16b, v8b, NODES);
    k_attn_mix   <<<ANB, 256, 0, stream>>>(qsb, k16b, v8b, rowptr, deg, csr, h1);
    k_bnstats    <<<SNB, 256, 0, stream>>>(h1, sum1, sq1);
    k_bnapply_f16<<<APB, 256, 0, stream>>>(h1, sum1, sq1, g1, be1, abuf);

    // layer 2
    k_gemm_f16   <<<GB, 256, 0, stream>>>(abuf, wt2, b2f, qsb, k16b, v8b, NODES);
    k_attn_mix   <<<ANB, 256, 0, stream>>>(qsb, k16b, v8b, rowptr, deg, csr, h1);
    k_bnstats    <<<SNB, 256, 0, stream>>>(h1, sum2, sq2);
    k_bnapply    <<<APB, 256, 0, stream>>>(h1, sum2, sq2, g2, be2, (float*)d_out);
}

// Round 14
// 444.256 us; speedup vs baseline: 1.1309x; 1.0190x over previous
//
#include <hip/hip_runtime.h>
#include <math.h>

#define NODES 30000
#define EDGES 600000
#define QS_W 512     // fp16 row: [q 256 | s 256]
#define K_W 256      // fp16 k row: 256 ushorts (512 B)
#define KV_W 256     // fp8 v row: 256 bytes
#define OUT_W 256
#define BN_EPS 1e-5f

typedef _Float16 f16x8 __attribute__((ext_vector_type(8)));
typedef _Float16 half2t __attribute__((ext_vector_type(2)));
typedef float f32x2 __attribute__((ext_vector_type(2)));
typedef __attribute__((ext_vector_type(4))) float f32x4;

__device__ __forceinline__ unsigned short f2h(float f) {
    union { _Float16 h; unsigned short u; } v;
    v.h = (_Float16)f;                      // v_cvt_f16_f32 (RNE)
    return v.u;
}
__device__ __forceinline__ float h2f(unsigned short u) {
    union { unsigned short u; _Float16 h; } v; v.u = u;
    return (float)v.h;
}
__device__ __forceinline__ half2t u2h2(unsigned int u) {
    union { unsigned int u; half2t h; } v; v.u = u;
    return v.h;
}

__device__ __forceinline__ float fdot2(half2t a, half2t b, float c) {
#if __has_builtin(__builtin_amdgcn_fdot2)
    return __builtin_amdgcn_fdot2(a, b, c, false);
#else
    return fmaf((float)a.x, (float)b.x, fmaf((float)a.y, (float)b.y, c));
#endif
}

// ---- OCP e4m3 pack/unpack (HW cvt when available; exact bit-math fallback) ----
// fallback math: e4m3 bits<<7 reinterpreted as fp16 = value * 2^-8 (exact incl. denorms)

__device__ __forceinline__ void dec8(uint2 w, float* f) {
#if __has_builtin(__builtin_amdgcn_cvt_pk_f32_fp8)
    f32x2 a = __builtin_amdgcn_cvt_pk_f32_fp8((int)w.x, false);
    f32x2 b = __builtin_amdgcn_cvt_pk_f32_fp8((int)w.x, true);
    f32x2 c = __builtin_amdgcn_cvt_pk_f32_fp8((int)w.y, false);
    f32x2 d = __builtin_amdgcn_cvt_pk_f32_fp8((int)w.y, true);
    f[0] = a.x; f[1] = a.y; f[2] = b.x; f[3] = b.y;
    f[4] = c.x; f[5] = c.y; f[6] = d.x; f[7] = d.y;
#else
    #pragma unroll
    for (int j = 0; j < 8; j++) {
        unsigned int byte = ((j < 4 ? w.x : w.y) >> ((j & 3) * 8)) & 0xFF;
        unsigned short h = (unsigned short)(((byte & 0x80u) << 8) | ((byte & 0x7Fu) << 7));
        f[j] = h2f(h) * 256.0f;
    }
#endif
}

__device__ __forceinline__ uint2 enc8(uint4 w) {
    float f[8];
    f[0] = h2f((unsigned short)(w.x & 0xffff)); f[1] = h2f((unsigned short)(w.x >> 16));
    f[2] = h2f((unsigned short)(w.y & 0xffff)); f[3] = h2f((unsigned short)(w.y >> 16));
    f[4] = h2f((unsigned short)(w.z & 0xffff)); f[5] = h2f((unsigned short)(w.z >> 16));
    f[6] = h2f((unsigned short)(w.w & 0xffff)); f[7] = h2f((unsigned short)(w.w >> 16));
    uint2 r;
#if __has_builtin(__builtin_amdgcn_cvt_pk_fp8_f32)
    int lo = 0, hi = 0;
    lo = __builtin_amdgcn_cvt_pk_fp8_f32(f[0], f[1], lo, false);
    lo = __builtin_amdgcn_cvt_pk_fp8_f32(f[2], f[3], lo, true);
    hi = __builtin_amdgcn_cvt_pk_fp8_f32(f[4], f[5], hi, false);
    hi = __builtin_amdgcn_cvt_pk_fp8_f32(f[6], f[7], hi, true);
    r.x = (unsigned)lo; r.y = (unsigned)hi;
#else
    unsigned b[8];
    #pragma unroll
    for (int j = 0; j < 8; j++) {
        unsigned short hb = f2h(f[j] * 0.00390625f);   // *2^-8
        unsigned m = hb & 0x7fffu;
        unsigned rr = m + 0x3Fu + ((m >> 7) & 1u);     // RNE on dropped 7 bits
        b[j] = ((hb >> 8) & 0x80u) | ((rr >> 7) & 0x7Fu);
    }
    r.x = b[0] | (b[1] << 8) | (b[2] << 16) | (b[3] << 24);
    r.y = b[4] | (b[5] << 8) | (b[6] << 16) | (b[7] << 24);
#endif
    return r;
}

// butterfly add via DPP (VALU pipe). 0xB1=xor1, 0x4E=xor2, 0x141=row_half_mirror(^4 after folds)
template<int CTRL>
__device__ __forceinline__ float dpp_xor_add(float x) {
    int xi = __builtin_bit_cast(int, x);
    int yi = __builtin_amdgcn_mov_dpp(xi, CTRL, 0xF, 0xF, true);
    return x + __builtin_bit_cast(float, yi);
}

typedef const __attribute__((address_space(1))) void* gas_p;
typedef __attribute__((address_space(3))) void* las_p;
__device__ __forceinline__ void gload_lds16(const void* g, void* l) {
    __builtin_amdgcn_global_load_lds((gas_p)g, (las_p)l, 16, 0, 0);
}

// ---------------- init: zero deg + BN sum arrays (replaces 2 memset dispatches) ----------------

__global__ __launch_bounds__(256) void k_init(int* __restrict__ deg, float* __restrict__ sums) {
    int i = blockIdx.x * 256 + threadIdx.x;
    if (i < NODES) deg[i] = 0;
    if (blockIdx.x == 0) {
        // 1024 floats (sum1|sq1|sum2|sq2 contiguous), 4 per thread
        #pragma unroll
        for (int j = 0; j < 4; j++) sums[threadIdx.x * 4 + j] = 0.f;
    }
}

// ---------------- CSR build (parallel 3-kernel scan; single-block scan regressed r12) ----------

__global__ __launch_bounds__(256) void k_count(const int* __restrict__ ei, int* __restrict__ deg) {
    int e = blockIdx.x * 256 + threadIdx.x;
    if (e < EDGES) atomicAdd(&deg[ei[EDGES + e]], 1);   // dst row
}

__global__ __launch_bounds__(256) void k_blocksum(const int* __restrict__ deg, int* __restrict__ bsum) {
    __shared__ int sh[256];
    int i = blockIdx.x * 256 + threadIdx.x;
    sh[threadIdx.x] = (i < NODES) ? deg[i] : 0;
    __syncthreads();
    for (int off = 128; off > 0; off >>= 1) {
        if (threadIdx.x < off) sh[threadIdx.x] += sh[threadIdx.x + off];
        __syncthreads();
    }
    if (threadIdx.x == 0) bsum[blockIdx.x] = sh[0];
}

__global__ __launch_bounds__(128) void k_scanb(const int* __restrict__ bsum, int* __restrict__ bbase, int nb) {
    __shared__ int sh[128];
    int t = threadIdx.x;
    int v = (t < nb) ? bsum[t] : 0;
    sh[t] = v;
    __syncthreads();
    for (int off = 1; off < 128; off <<= 1) {
        int add = (t >= off) ? sh[t - off] : 0;
        __syncthreads();
        sh[t] += add;
        __syncthreads();
    }
    if (t < nb) bbase[t] = sh[t] - v;   // exclusive
}

__global__ __launch_bounds__(256) void k_localscan(const int* __restrict__ deg, const int* __restrict__ bbase,
                                                   int* __restrict__ rowptr, int* __restrict__ cursor) {
    __shared__ int sh[256];
    int i = blockIdx.x * 256 + threadIdx.x;
    int v = (i < NODES) ? deg[i] : 0;
    sh[threadIdx.x] = v;
    __syncthreads();
    for (int off = 1; off < 256; off <<= 1) {
        int add = (threadIdx.x >= off) ? sh[threadIdx.x - off] : 0;
        __syncthreads();
        sh[threadIdx.x] += add;
        __syncthreads();
    }
    if (i < NODES) {
        int p = bbase[blockIdx.x] + sh[threadIdx.x] - v;  // exclusive
        rowptr[i] = p;
        cursor[i] = p;
    }
}

__global__ __launch_bounds__(256) void k_fill(const int* __restrict__ ei, int* __restrict__ cursor,
                                              int* __restrict__ csr_src) {
    int e = blockIdx.x * 256 + threadIdx.x;
    if (e < EDGES) {
        int s = ei[e];
        int d = ei[EDGES + e];
        int slot = atomicAdd(&cursor[d], 1);
        csr_src[slot] = s;
    }
}

// ---------------- fused cast: blocks [0,128) = W transpose-cast; rest = A cast ----------------

__global__ __launch_bounds__(256) void k_castAW(
    const float* __restrict__ x, unsigned short* __restrict__ abuf,
    const float* __restrict__ Wa0, const float* __restrict__ Wa1,
    const float* __restrict__ Wa2, const float* __restrict__ Wa3,
    const float* __restrict__ Ba0, const float* __restrict__ Ba1,
    const float* __restrict__ Ba2, const float* __restrict__ Ba3,
    const float* __restrict__ Wb0, const float* __restrict__ Wb1,
    const float* __restrict__ Wb2, const float* __restrict__ Wb3,
    const float* __restrict__ Bb0, const float* __restrict__ Bb1,
    const float* __restrict__ Bb2, const float* __restrict__ Bb3,
    unsigned short* __restrict__ Wt1, float* __restrict__ bf1,
    unsigned short* __restrict__ Wt2, float* __restrict__ bf2)
{
    __shared__ float tile[64][65];
    int b = blockIdx.x;
    if (b >= 128) {
        // ---- A cast: item index over NODES*256/8 = 960000
        int i = (b - 128) * 256 + threadIdx.x;
        if (i >= NODES * 256 / 8) return;
        const float4* p = (const float4*)(x + (size_t)i * 8);
        float4 v0 = p[0], v1 = p[1];
        ushort4 o0, o1;
        o0.x = f2h(v0.x); o0.y = f2h(v0.y); o0.z = f2h(v0.z); o0.w = f2h(v0.w);
        o1.x = f2h(v1.x); o1.y = f2h(v1.y); o1.z = f2h(v1.z); o1.w = f2h(v1.w);
        ushort4* q = (ushort4*)(abuf + (size_t)i * 8);
        q[0] = o0; q[1] = o1;
        return;
    }
    // ---- W transpose-cast
    int layer = b >> 6;
    int wsel = (b >> 4) & 3;
    int kt = (b >> 2) & 3;   // k-row tile of W (64 rows)
    int ct = b & 3;          // col tile of W (64 cols)
    const float* W; const float* Bv;
    if (layer == 0) {
        W  = (wsel == 0) ? Wa0 : (wsel == 1) ? Wa1 : (wsel == 2) ? Wa2 : Wa3;
        Bv = (wsel == 0) ? Ba0 : (wsel == 1) ? Ba1 : (wsel == 2) ? Ba2 : Ba3;
    } else {
        W  = (wsel == 0) ? Wb0 : (wsel == 1) ? Wb1 : (wsel == 2) ? Wb2 : Wb3;
        Bv = (wsel == 0) ? Bb0 : (wsel == 1) ? Bb1 : (wsel == 2) ? Bb2 : Bb3;
    }
    unsigned short* Wt = (layer == 0) ? Wt1 : Wt2;
    float* bfused = (layer == 0) ? bf1 : bf2;

    int t = threadIdx.x;
    int tr = t >> 4;           // 0..15
    int tc4 = (t & 15) * 4;    // 0,4,...,60
    #pragma unroll
    for (int r = 0; r < 64; r += 16) {
        float4 v = *(const float4*)&W[(size_t)(kt * 64 + tr + r) * 256 + ct * 64 + tc4];
        tile[tr + r][tc4 + 0] = v.x;
        tile[tr + r][tc4 + 1] = v.y;
        tile[tr + r][tc4 + 2] = v.z;
        tile[tr + r][tc4 + 3] = v.w;
    }
    __syncthreads();
    #pragma unroll
    for (int r = 0; r < 64; r += 16) {
        int nr = tr + r;                       // col-local of W == row-local of Wt
        ushort4 o;
        o.x = f2h(tile[tc4 + 0][nr]);
        o.y = f2h(tile[tc4 + 1][nr]);
        o.z = f2h(tile[tc4 + 2][nr]);
        o.w = f2h(tile[tc4 + 3][nr]);
        *(ushort4*)&Wt[(size_t)(wsel * 256 + ct * 64 + nr) * 256 + kt * 64 + tc4] = o;
    }
    if (kt == 0 && t < 64) bfused[wsel * 256 + ct * 64 + t] = Bv[ct * 64 + t];
}

// ---------------- fp16 MFMA GEMM; XCD swizzle + T2 LDS XOR-swizzle (this round's change) --------
// LDS tiles are [128][64] fp16 = 128B row stride: a fragment ds_read_b128 had lanes 0-15
// reading 16 different ROWS at the same 16B chunk -> same bank -> 16-way conflict (G4).
// Fix per rule #21 (gload_lds forbids LDS-side swizzle/padding): keep LDS dest LINEAR and
// pre-swizzle the GLOBAL source column: LDS chunk (row, c) holds global col c^(row&7);
// reads XOR the same key (lane&7 == row&7). Involution both sides -> values bit-identical.
// Bank spread per read: 16-way -> 8-way (geometry caps at 8 chunk-groups/row).

#define CS 136   // padded LDS stride (ushorts) for the 128x128 C tile

__global__ __launch_bounds__(256) void k_gemm_f16(
    const unsigned short* __restrict__ A,
    const unsigned short* __restrict__ Wt,
    const float* __restrict__ bias,
    unsigned short* __restrict__ QS,
    unsigned short* __restrict__ K16,
    unsigned char* __restrict__ V8, int M)
{
    __shared__ unsigned short sbuf[128 * CS];   // 34,816 B; unions staging (32KB) and epilogue
    unsigned short* As = sbuf;                  // 128*64
    unsigned short* Bs = sbuf + 8192;           // 128*64
    int tid = threadIdx.x;
    int lane = tid & 63;
    int wave = tid >> 6;
    int wm = wave & 1, wn = wave >> 1;      // 2x2 waves -> 64x64 each

    // XCD-chunked swizzle: xcd = bid%8 owns sbid range [xcd*235, (xcd+1)*235)
    int bid = blockIdx.x;
    int sbid = (bid & 7) * 235 + (bid >> 3);
    int row0 = (sbid >> 3) * 128;           // row-block   (0..234)
    int n0 = (sbid & 7) * 128;              // col-block in fused 1024-col space

    f32x4 acc[4][4] = {};

    for (int k0 = 0; k0 < 256; k0 += 64) {
        #pragma unroll
        for (int w = 0; w < 4; w++) {
            int c = w * 256 + tid;
            int row = c >> 3;
            int cole = (((c & 7) ^ (row & 7)) * 8);  // pre-swizzled source column (T2/m173)
            int ar = row0 + row; if (ar >= M) ar = M - 1;
            gload_lds16(&A[(size_t)ar * 256 + k0 + cole], &As[w * 2048 + tid * 8]);
            gload_lds16(&Wt[(size_t)(n0 + row) * 256 + k0 + cole], &Bs[w * 2048 + tid * 8]);
        }
        __syncthreads();
        int rsel = lane & 15;
        int qk = lane >> 4;                 // k-quad 0..3
        int key = lane & 7;                 // == row&7 for this lane's rows
        #pragma unroll
        for (int kh = 0; kh < 2; kh++) {
            f16x8 af[4], bfr[4];
            #pragma unroll
            for (int t = 0; t < 4; t++) {
                int ch = ((kh * 4 + qk) ^ key) * 8;   // swizzled chunk (same involution)
                af[t]  = *reinterpret_cast<const f16x8*>(&As[(wm * 64 + t * 16 + rsel) * 64 + ch]);
                bfr[t] = *reinterpret_cast<const f16x8*>(&Bs[(wn * 64 + t * 16 + rsel) * 64 + ch]);
            }
            #pragma unroll
            for (int mt = 0; mt < 4; mt++)
                #pragma unroll
                for (int nt = 0; nt < 4; nt++)
                    acc[mt][nt] = __builtin_amdgcn_mfma_f32_16x16x32_f16(af[mt], bfr[nt], acc[mt][nt], 0, 0, 0);
        }
        __syncthreads();
    }

    // epilogue: stage fp16(+bias) tile into padded LDS (C/D map: col=lane&15, row=(lane>>4)*4+reg)
    int crow = (lane >> 4) * 4;
    int ccol = lane & 15;
    #pragma unroll
    for (int mt = 0; mt < 4; mt++) {
        int lrow = wm * 64 + mt * 16 + crow;
        #pragma unroll
        for (int nt = 0; nt < 4; nt++) {
            int lcol = wn * 64 + nt * 16 + ccol;
            float bv = bias[n0 + lcol];
            #pragma unroll
            for (int r = 0; r < 4; r++)
                sbuf[(lrow + r) * CS + lcol] = f2h(acc[mt][nt][r] + bv);
        }
    }
    __syncthreads();
    int chunk = tid & 15;
    int rbase = tid >> 4;
    if (n0 < 256 || n0 >= 768) {
        // q (cols 0..255) or s (768..1023) -> fp16 qs rows [q|s]
        int cbase = (n0 < 256) ? n0 : (n0 - 512);
        #pragma unroll
        for (int g = 0; g < 8; g++) {
            int row_l = g * 16 + rbase;
            int gr = row0 + row_l;
            if (gr < M) {
                uint4 val = *(const uint4*)&sbuf[row_l * CS + chunk * 8];
                *(uint4*)&QS[(size_t)gr * QS_W + cbase + chunk * 8] = val;
            }
        }
    } else if (n0 < 512) {
        // k (256..511) -> K16 fp16 compact rows
        int cbase = n0 - 256;
        #pragma unroll
        for (int g = 0; g < 8; g++) {
            int row_l = g * 16 + rbase;
            int gr = row0 + row_l;
            if (gr < M) {
                uint4 val = *(const uint4*)&sbuf[row_l * CS + chunk * 8];
                *(uint4*)&K16[(size_t)gr * K_W + cbase + chunk * 8] = val;
            }
        }
    } else {
        // v (512..767) -> V8 fp8 e4m3 compact rows
        int cbase = n0 - 512;
        #pragma unroll
        for (int g = 0; g < 8; g++) {
            int row_l = g * 16 + rbase;
            int gr = row0 + row_l;
            if (gr < M) {
                uint4 val = *(const uint4*)&sbuf[row_l * CS + chunk * 8];
                uint2 enc = enc8(val);
                *(uint2*)&V8[(size_t)gr * KV_W + cbase + chunk * 8] = enc;
            }
        }
    }
}

// ---------------- attention (fp16 q/k/s, fp8 v): one wave per node, half-wave split ----------------
// BIT-IDENTICAL to round 8 (best verified: ~66us, absmax 0.1015625, at gather-service floor).

__global__ __launch_bounds__(256) void k_attn_mix(const unsigned short* __restrict__ qs,
                                                  const unsigned short* __restrict__ k16,
                                                  const unsigned char* __restrict__ v8,
                                                  const int* __restrict__ rowptr,
                                                  const int* __restrict__ deg,
                                                  const int* __restrict__ csr_src,
                                                  float* __restrict__ out)
{
    int wave = threadIdx.x >> 6;
    int lane = threadIdx.x & 63;
    int node = blockIdx.x * 4 + wave;
    if (node >= NODES) return;
    int half = lane >> 5;
    int lh = lane & 31;

    const unsigned short* qrow = qs + (size_t)node * QS_W;
    uint4 qv = *(const uint4*)&qrow[lh * 8];   // stays packed; fdot2 consumes half2 directly

    int start = rowptr[node];
    int cnt = deg[node];

    float m = -INFINITY, L = 0.f;
    float acc[8] = {0.f, 0.f, 0.f, 0.f, 0.f, 0.f, 0.f, 0.f};

    if (cnt > 0) {
        int clast = cnt - 1;
        #define CPOS(p) (start + (((2 * (p) + half) > clast) ? clast : (2 * (p) + half)))
        int i0  = csr_src[CPOS(0)];
        int i1  = csr_src[CPOS(1)];
        int ixA = csr_src[CPOS(2)];
        int ixB = csr_src[CPOS(3)];
        uint4 kA, kB;
        uint2 vA, vB;
        kA = *(const uint4*)&k16[(size_t)i0 * K_W + lh * 8];
        vA = *(const uint2*)&v8[(size_t)i0 * KV_W + lh * 8];
        kB = *(const uint4*)&k16[(size_t)i1 * K_W + lh * 8];
        vB = *(const uint2*)&v8[(size_t)i1 * KV_W + lh * 8];
        int npairs = (cnt + 1) >> 1;
        for (int i = 0; i < npairs; i += 2) {
            // ========== sub-iter A: pair i (slot A) ==========
            {
                const unsigned short* pkA = k16 + (size_t)ixA * K_W + lh * 8;
                const unsigned char*  pvA = v8  + (size_t)ixA * KV_W + lh * 8;
                ixA = csr_src[CPOS(i + 4)];              // refill index slot (distance 4)
                float d  = fdot2(u2h2(qv.x), u2h2(kA.x), 0.f);
                d        = fdot2(u2h2(qv.y), u2h2(kA.y), d);
                float d2 = fdot2(u2h2(qv.z), u2h2(kA.z), 0.f);
                d2       = fdot2(u2h2(qv.w), u2h2(kA.w), d2);
                d += d2;
                kA = *(const uint4*)pkA;                 // reload slot (pair i+2)
                d = dpp_xor_add<0xB1>(d);                // xor1
                d = dpp_xor_add<0x4E>(d);                // xor2
                d = dpp_xor_add<0x141>(d);               // xor4 (row_half_mirror)
                float al = d * 0.125f;                   // / sqrt(64)
                bool valid = (2 * i + half) < cnt;
                if (valid) {
                    if (__any(al > m + 8.f)) {           // defer-max: rescale rarely
                        float nm = fmaxf(m, al);
                        float sc = __expf(m - nm);       // exp(-inf)=0 on first edge
                        L *= sc;
                        #pragma unroll
                        for (int t = 0; t < 8; t++) acc[t] *= sc;
                        m = nm;
                    }
                    float p = __expf(al - m);            // bounded by e^8
                    L += p;
                    float vf[8];
                    dec8(vA, vf);
                    #pragma unroll
                    for (int t = 0; t < 8; t++) acc[t] = fmaf(p, vf[t], acc[t]);
                }
                vA = *(const uint2*)pvA;                 // reload slot (pair i+2)
            }
            // ========== sub-iter B: pair i+1 (slot B) ==========
            {
                const unsigned short* pkB = k16 + (size_t)ixB * K_W + lh * 8;
                const unsigned char*  pvB = v8  + (size_t)ixB * KV_W + lh * 8;
                ixB = csr_src[CPOS(i + 5)];              // refill index slot (distance 4)
                float d  = fdot2(u2h2(qv.x), u2h2(kB.x), 0.f);
                d        = fdot2(u2h2(qv.y), u2h2(kB.y), d);
                float d2 = fdot2(u2h2(qv.z), u2h2(kB.z), 0.f);
                d2       = fdot2(u2h2(qv.w), u2h2(kB.w), d2);
                d += d2;
                kB = *(const uint4*)pkB;                 // reload slot (pair i+3)
                d = dpp_xor_add<0xB1>(d);
                d = dpp_xor_add<0x4E>(d);
                d = dpp_xor_add<0x141>(d);
                float al = d * 0.125f;
                bool valid = (2 * (i + 1) + half) < cnt;
                if (valid) {
                    if (__any(al > m + 8.f)) {
                        float nm = fmaxf(m, al);
                        float sc = __expf(m - nm);
                        L *= sc;
                        #pragma unroll
                        for (int t = 0; t < 8; t++) acc[t] *= sc;
                        m = nm;
                    }
                    float p = __expf(al - m);
                    L += p;
                    float vf[8];
                    dec8(vB, vf);
                    #pragma unroll
                    for (int t = 0; t < 8; t++) acc[t] = fmaf(p, vf[t], acc[t]);
                }
                vB = *(const uint2*)pvB;                 // reload slot (pair i+3)
            }
        }
        #undef CPOS
    }

    // ---- merge the two half-wave softmax states
    float mo = __shfl_xor(m, 32, 64);
    float Lo = __shfl_xor(L, 32, 64);
    float nm = fmaxf(m, mo);
    float scs = (L  > 0.f) ? __expf(m  - nm) : 0.f;   // guards cnt==0 / single-edge
    float sco = (Lo > 0.f) ? __expf(mo - nm) : 0.f;
    float Lt = fmaf(L, scs, Lo * sco);
    float inv = (Lt > 0.f) ? 1.f / Lt : 0.f;
    float t0 = fmaf(acc[0], scs, __shfl_xor(acc[0], 32, 64) * sco);
    float t1 = fmaf(acc[1], scs, __shfl_xor(acc[1], 32, 64) * sco);
    float t2 = fmaf(acc[2], scs, __shfl_xor(acc[2], 32, 64) * sco);
    float t3 = fmaf(acc[3], scs, __shfl_xor(acc[3], 32, 64) * sco);
    float t4 = fmaf(acc[4], scs, __shfl_xor(acc[4], 32, 64) * sco);
    float t5 = fmaf(acc[5], scs, __shfl_xor(acc[5], 32, 64) * sco);
    float t6 = fmaf(acc[6], scs, __shfl_xor(acc[6], 32, 64) * sco);
    float t7 = fmaf(acc[7], scs, __shfl_xor(acc[7], 32, 64) * sco);
    // lane writes 4 of its 8 channels: lo half -> ch 8lh+0..3, hi half -> ch 8lh+4..7
    float w0 = half ? t4 : t0;
    float w1 = half ? t5 : t1;
    float w2 = half ? t6 : t2;
    float w3 = half ? t7 : t3;
    ushort4 sv = *(const ushort4*)&qrow[256 + lh * 8 + half * 4];   // s block
    float4 o;
    o.x = fmaf(w0, inv, h2f(sv.x));
    o.y = fmaf(w1, inv, h2f(sv.y));
    o.z = fmaf(w2, inv, h2f(sv.z));
    o.w = fmaf(w3, inv, h2f(sv.w));
    *(float4*)&out[(size_t)node * OUT_W + lh * 8 + half * 4] = o;
}

// ---------------- BatchNorm ----------------

__global__ __launch_bounds__(256) void k_bnstats(const float* __restrict__ h,
                                                 float* __restrict__ sum, float* __restrict__ sumsq) {
    int col = threadIdx.x;
    int r0 = blockIdx.x * 64;
    int r1 = min(r0 + 64, NODES);
    float s = 0.f, s2 = 0.f;
    for (int r = r0; r < r1; r++) {
        float v = h[(size_t)r * OUT_W + col];
        s += v; s2 += v * v;
    }
    atomicAdd(&sum[col], s);
    atomicAdd(&sumsq[col], s2);
}

__device__ __forceinline__ float4 bn_scale4(const float* sum, const float* sumsq,
                                            const float* g, const float* be,
                                            int col, float4* shift) {
    float4 s  = *(const float4*)&sum[col];
    float4 s2 = *(const float4*)&sumsq[col];
    float4 gv = *(const float4*)&g[col];
    float4 bv = *(const float4*)&be[col];
    const float invN = 1.0f / NODES;
    float4 sc, sh;
    float mean, var;
    mean = s.x * invN; var = fmaxf(s2.x * invN - mean * mean, 0.f);
    sc.x = gv.x * rsqrtf(var + BN_EPS); sh.x = bv.x - mean * sc.x;
    mean = s.y * invN; var = fmaxf(s2.y * invN - mean * mean, 0.f);
    sc.y = gv.y * rsqrtf(var + BN_EPS); sh.y = bv.y - mean * sc.y;
    mean = s.z * invN; var = fmaxf(s2.z * invN - mean * mean, 0.f);
    sc.z = gv.z * rsqrtf(var + BN_EPS); sh.z = bv.z - mean * sc.z;
    mean = s.w * invN; var = fmaxf(s2.w * invN - mean * mean, 0.f);
    sc.w = gv.w * rsqrtf(var + BN_EPS); sh.w = bv.w - mean * sc.w;
    *shift = sh;
    return sc;
}

// layer-1 apply: fp32 in -> fp16 out (feeds GEMM2)
__global__ __launch_bounds__(256) void k_bnapply_f16(const float* __restrict__ h,
                                                     const float* __restrict__ sum,
                                                     const float* __restrict__ sumsq,
                                                     const float* __restrict__ g,
                                                     const float* __restrict__ be,
                                                     unsigned short* __restrict__ out) {
    int idx = blockIdx.x * 256 + threadIdx.x;
    int base = idx * 4;
    int col = base & (OUT_W - 1);
    float4 sh;
    float4 sc = bn_scale4(sum, sumsq, g, be, col, &sh);
    float4 v = *(const float4*)&h[base];
    float4 o;
    o.x = v.x * sc.x + sh.x; o.x = (o.x >= 0.f) ? o.x : 0.1f * o.x;
    o.y = v.y * sc.y + sh.y; o.y = (o.y >= 0.f) ? o.y : 0.1f * o.y;
    o.z = v.z * sc.z + sh.z; o.z = (o.z >= 0.f) ? o.z : 0.1f * o.z;
    o.w = v.w * sc.w + sh.w; o.w = (o.w >= 0.f) ? o.w : 0.1f * o.w;
    ushort4 u; u.x = f2h(o.x); u.y = f2h(o.y); u.z = f2h(o.z); u.w = f2h(o.w);
    *(ushort4*)&out[base] = u;
}

// layer-2 apply: fp32 in -> fp32 out (final output)
__global__ __launch_bounds__(256) void k_bnapply(const float* __restrict__ h,
                                                 const float* __restrict__ sum,
                                                 const float* __restrict__ sumsq,
                                                 const float* __restrict__ g,
                                                 const float* __restrict__ be,
                                                 float* __restrict__ out) {
    int idx = blockIdx.x * 256 + threadIdx.x;
    int base = idx * 4;
    int col = base & (OUT_W - 1);
    float4 sh;
    float4 sc = bn_scale4(sum, sumsq, g, be, col, &sh);
    float4 v = *(const float4*)&h[base];
    float4 o;
    o.x = v.x * sc.x + sh.x; o.x = (o.x >= 0.f) ? o.x : 0.1f * o.x;
    o.y = v.y * sc.y + sh.y; o.y = (o.y >= 0.f) ? o.y : 0.1f * o.y;
    o.z = v.z * sc.z + sh.z; o.z = (o.z >= 0.f) ? o.z : 0.1f * o.z;
    o.w = v.w * sc.w + sh.w; o.w = (o.w >= 0.f) ? o.w : 0.1f * o.w;
    *(float4*)&out[base] = o;
}

// ---------------- launch ----------------
// Same 15-dispatch chain as r13; only k_gemm_f16 internals changed (T2 LDS swizzle).

extern "C" void kernel_launch(void* const* d_in, const int* in_sizes, int n_in,
                              void* d_out, int out_size, void* d_ws, size_t ws_size,
                              hipStream_t stream) {
    const float* x  = (const float*)d_in[0];
    const int*   ei = (const int*)d_in[1];
    const float* w1[4] = {(const float*)d_in[2], (const float*)d_in[4], (const float*)d_in[6], (const float*)d_in[8]};
    const float* b1[4] = {(const float*)d_in[3], (const float*)d_in[5], (const float*)d_in[7], (const float*)d_in[9]};
    const float* g1  = (const float*)d_in[10];
    const float* be1 = (const float*)d_in[11];
    const float* w2[4] = {(const float*)d_in[12], (const float*)d_in[14], (const float*)d_in[16], (const float*)d_in[18]};
    const float* b2[4] = {(const float*)d_in[13], (const float*)d_in[15], (const float*)d_in[17], (const float*)d_in[19]};
    const float* g2  = (const float*)d_in[20];
    const float* be2 = (const float*)d_in[21];

    char* ws = (char*)d_ws;
    unsigned short* qsb    = (unsigned short*)(ws);                 // 30,720,000 (fp16 [q|s])
    unsigned short* k16b   = (unsigned short*)(ws + 30720000);      // 15,360,000 (fp16 k)
    unsigned char*  v8b    = (unsigned char*)(ws + 46080000);       //  7,680,000 (fp8 v)
    float*          h1     = (float*)(ws + 53760000);               // 30,720,000
    unsigned short* abuf   = (unsigned short*)(ws + 84480000);      // 15,360,000 (fp16 GEMM input)
    unsigned short* wt1    = (unsigned short*)(ws + 99840000);      // 524,288
    unsigned short* wt2    = (unsigned short*)(ws + 100364288);     // 524,288
    float*          b1f    = (float*)(ws + 100888576);              // 4,096
    float*          b2f    = (float*)(ws + 100892672);              // 4,096
    int*            deg    = (int*)  (ws + 100896768);              // 120,000
    int*            rowptr = (int*)  (ws + 101016768);              // 120,000
    int*            cursor = (int*)  (ws + 101136768);              // 120,000
    int*            csr    = (int*)  (ws + 101256768);              // 2,400,000
    int*            bsum   = (int*)  (ws + 103656768);              // 512
    int*            bbase  = (int*)  (ws + 103657280);              // 512
    float*          sum1   = (float*)(ws + 103657792);              // 4 x 1024 B contiguous
    float*          sq1    = (float*)(ws + 103658816);
    float*          sum2   = (float*)(ws + 103659840);
    float*          sq2    = (float*)(ws + 103660864);

    const int EB = (EDGES + 255) / 256;       // 2344
    const int NB = (NODES + 255) / 256;       // 118

    k_init   <<<NB, 256, 0, stream>>>(deg, sum1);      // deg + all 4 BN sum arrays
    k_castAW <<<128 + (NODES * 256 / 8 + 255) / 256, 256, 0, stream>>>(
        x, abuf,
        w1[0], w1[1], w1[2], w1[3], b1[0], b1[1], b1[2], b1[3],
        w2[0], w2[1], w2[2], w2[3], b2[0], b2[1], b2[2], b2[3],
        wt1, b1f, wt2, b2f);

    // CSR (shared by both layers) — parallel scan chain
    k_count    <<<EB, 256, 0, stream>>>(ei, deg);
    k_blocksum <<<NB, 256, 0, stream>>>(deg, bsum);
    k_scanb    <<<1, 128, 0, stream>>>(bsum, bbase, NB);
    k_localscan<<<NB, 256, 0, stream>>>(deg, bbase, rowptr, cursor);
    k_fill     <<<EB, 256, 0, stream>>>(ei, cursor, csr);

    const int GB = 235 * 8;                   // 1880 blocks, XCD-swizzled in-kernel
    const int ANB = NODES / 4;                // 7500
    const int APB = (NODES * OUT_W / 4) / 256;// 7500
    const int SNB = (NODES + 63) / 64;        // 469

    // layer 1
    k_gemm_f16   <<<GB, 256, 0, stream>>>(abuf, wt1, b1f, qsb, k16b, v8b, NODES);
    k_attn_mix   <<<ANB, 256, 0, stream>>>(qsb, k16b, v8b, rowptr, deg, csr, h1);
    k_bnstats    <<<SNB, 256, 0, stream>>>(h1, sum1, sq1);
    k_bnapply_f16<<<APB, 256, 0, stream>>>(h1, sum1, sq1, g1, be1, abuf);

    // layer 2
    k_gemm_f16   <<<GB, 256, 0, stream>>>(abuf, wt2, b2f, qsb, k16b, v8b, NODES);
    k_attn_mix   <<<ANB, 256, 0, stream>>>(qsb, k16b, v8b, rowptr, deg, csr, h1);
    k_bnstats    <<<SNB, 256, 0, stream>>>(h1, sum2, sq2);
    k_bnapply    <<<APB, 256, 0, stream>>>(h1, sum2, sq2, g2, be2, (float*)d_out);
}

// Round 15
// 443.227 us; speedup vs baseline: 1.1335x; 1.0023x over previous
//
#include <hip/hip_runtime.h>
#include <math.h>

#define NODES 30000
#define EDGES 600000
#define QS_W 512     // fp16 row: [q 256 | s 256]
#define K_W 256      // fp16 k row: 256 ushorts (512 B)
#define KV_W 256     // fp8 v row: 256 bytes
#define OUT_W 256
#define BN_EPS 1e-5f

typedef _Float16 f16x8 __attribute__((ext_vector_type(8)));
typedef _Float16 half2t __attribute__((ext_vector_type(2)));
typedef float f32x2 __attribute__((ext_vector_type(2)));
typedef __attribute__((ext_vector_type(4))) float f32x4;

__device__ __forceinline__ unsigned short f2h(float f) {
    union { _Float16 h; unsigned short u; } v;
    v.h = (_Float16)f;                      // v_cvt_f16_f32 (RNE)
    return v.u;
}
__device__ __forceinline__ float h2f(unsigned short u) {
    union { unsigned short u; _Float16 h; } v; v.u = u;
    return (float)v.h;
}
__device__ __forceinline__ half2t u2h2(unsigned int u) {
    union { unsigned int u; half2t h; } v; v.u = u;
    return v.h;
}

__device__ __forceinline__ float fdot2(half2t a, half2t b, float c) {
#if __has_builtin(__builtin_amdgcn_fdot2)
    return __builtin_amdgcn_fdot2(a, b, c, false);
#else
    return fmaf((float)a.x, (float)b.x, fmaf((float)a.y, (float)b.y, c));
#endif
}

// ---- OCP e4m3 pack/unpack (HW cvt when available; exact bit-math fallback) ----

__device__ __forceinline__ void dec8(uint2 w, float* f) {
#if __has_builtin(__builtin_amdgcn_cvt_pk_f32_fp8)
    f32x2 a = __builtin_amdgcn_cvt_pk_f32_fp8((int)w.x, false);
    f32x2 b = __builtin_amdgcn_cvt_pk_f32_fp8((int)w.x, true);
    f32x2 c = __builtin_amdgcn_cvt_pk_f32_fp8((int)w.y, false);
    f32x2 d = __builtin_amdgcn_cvt_pk_f32_fp8((int)w.y, true);
    f[0] = a.x; f[1] = a.y; f[2] = b.x; f[3] = b.y;
    f[4] = c.x; f[5] = c.y; f[6] = d.x; f[7] = d.y;
#else
    #pragma unroll
    for (int j = 0; j < 8; j++) {
        unsigned int byte = ((j < 4 ? w.x : w.y) >> ((j & 3) * 8)) & 0xFF;
        unsigned short h = (unsigned short)(((byte & 0x80u) << 8) | ((byte & 0x7Fu) << 7));
        f[j] = h2f(h) * 256.0f;
    }
#endif
}

__device__ __forceinline__ uint2 enc8(uint4 w) {
    float f[8];
    f[0] = h2f((unsigned short)(w.x & 0xffff)); f[1] = h2f((unsigned short)(w.x >> 16));
    f[2] = h2f((unsigned short)(w.y & 0xffff)); f[3] = h2f((unsigned short)(w.y >> 16));
    f[4] = h2f((unsigned short)(w.z & 0xffff)); f[5] = h2f((unsigned short)(w.z >> 16));
    f[6] = h2f((unsigned short)(w.w & 0xffff)); f[7] = h2f((unsigned short)(w.w >> 16));
    uint2 r;
#if __has_builtin(__builtin_amdgcn_cvt_pk_fp8_f32)
    int lo = 0, hi = 0;
    lo = __builtin_amdgcn_cvt_pk_fp8_f32(f[0], f[1], lo, false);
    lo = __builtin_amdgcn_cvt_pk_fp8_f32(f[2], f[3], lo, true);
    hi = __builtin_amdgcn_cvt_pk_fp8_f32(f[4], f[5], hi, false);
    hi = __builtin_amdgcn_cvt_pk_fp8_f32(f[6], f[7], hi, true);
    r.x = (unsigned)lo; r.y = (unsigned)hi;
#else
    unsigned b[8];
    #pragma unroll
    for (int j = 0; j < 8; j++) {
        unsigned short hb = f2h(f[j] * 0.00390625f);   // *2^-8
        unsigned m = hb & 0x7fffu;
        unsigned rr = m + 0x3Fu + ((m >> 7) & 1u);     // RNE on dropped 7 bits
        b[j] = ((hb >> 8) & 0x80u) | ((rr >> 7) & 0x7Fu);
    }
    r.x = b[0] | (b[1] << 8) | (b[2] << 16) | (b[3] << 24);
    r.y = b[4] | (b[5] << 8) | (b[6] << 16) | (b[7] << 24);
#endif
    return r;
}

// butterfly add via DPP (VALU pipe). 0xB1=xor1, 0x4E=xor2, 0x141=row_half_mirror(^4 after folds)
template<int CTRL>
__device__ __forceinline__ float dpp_xor_add(float x) {
    int xi = __builtin_bit_cast(int, x);
    int yi = __builtin_amdgcn_mov_dpp(xi, CTRL, 0xF, 0xF, true);
    return x + __builtin_bit_cast(float, yi);
}

typedef const __attribute__((address_space(1))) void* gas_p;
typedef __attribute__((address_space(3))) void* las_p;
__device__ __forceinline__ void gload_lds16(const void* g, void* l) {
    __builtin_amdgcn_global_load_lds((gas_p)g, (las_p)l, 16, 0, 0);
}

// ---------------- init: zero deg + BN sum arrays ----------------

__global__ __launch_bounds__(256) void k_init(int* __restrict__ deg, float* __restrict__ sums) {
    int i = blockIdx.x * 256 + threadIdx.x;
    if (i < NODES) deg[i] = 0;
    if (blockIdx.x == 0) {
        #pragma unroll
        for (int j = 0; j < 4; j++) sums[threadIdx.x * 4 + j] = 0.f;
    }
}

// ---------------- k_pre: fused {W transpose-cast | A cast | edge count} ----------------
// blocks [0,128): W; [128,3878): A; [3878,6222): count. All three are mutually
// independent (count needs deg pre-zeroed by k_init). Values bit-identical to split kernels.

#define PRE_WBLK 128
#define PRE_ABLK 3750           // NODES*256/8/256
#define PRE_CBLK 2344           // ceil(EDGES/256)

__global__ __launch_bounds__(256) void k_pre(
    const float* __restrict__ x, unsigned short* __restrict__ abuf,
    const int* __restrict__ ei, int* __restrict__ deg,
    const float* __restrict__ Wa0, const float* __restrict__ Wa1,
    const float* __restrict__ Wa2, const float* __restrict__ Wa3,
    const float* __restrict__ Ba0, const float* __restrict__ Ba1,
    const float* __restrict__ Ba2, const float* __restrict__ Ba3,
    const float* __restrict__ Wb0, const float* __restrict__ Wb1,
    const float* __restrict__ Wb2, const float* __restrict__ Wb3,
    const float* __restrict__ Bb0, const float* __restrict__ Bb1,
    const float* __restrict__ Bb2, const float* __restrict__ Bb3,
    unsigned short* __restrict__ Wt1, float* __restrict__ bf1,
    unsigned short* __restrict__ Wt2, float* __restrict__ bf2)
{
    __shared__ float tile[64][65];
    int b = blockIdx.x;
    if (b >= PRE_WBLK + PRE_ABLK) {
        // ---- edge count
        int e = (b - PRE_WBLK - PRE_ABLK) * 256 + threadIdx.x;
        if (e < EDGES) atomicAdd(&deg[ei[EDGES + e]], 1);   // dst row
        return;
    }
    if (b >= PRE_WBLK) {
        // ---- A cast
        int i = (b - PRE_WBLK) * 256 + threadIdx.x;
        if (i >= NODES * 256 / 8) return;
        const float4* p = (const float4*)(x + (size_t)i * 8);
        float4 v0 = p[0], v1 = p[1];
        ushort4 o0, o1;
        o0.x = f2h(v0.x); o0.y = f2h(v0.y); o0.z = f2h(v0.z); o0.w = f2h(v0.w);
        o1.x = f2h(v1.x); o1.y = f2h(v1.y); o1.z = f2h(v1.z); o1.w = f2h(v1.w);
        ushort4* q = (ushort4*)(abuf + (size_t)i * 8);
        q[0] = o0; q[1] = o1;
        return;
    }
    // ---- W transpose-cast (coalesced via 64x64 LDS tile)
    int layer = b >> 6;
    int wsel = (b >> 4) & 3;
    int kt = (b >> 2) & 3;
    int ct = b & 3;
    const float* W; const float* Bv;
    if (layer == 0) {
        W  = (wsel == 0) ? Wa0 : (wsel == 1) ? Wa1 : (wsel == 2) ? Wa2 : Wa3;
        Bv = (wsel == 0) ? Ba0 : (wsel == 1) ? Ba1 : (wsel == 2) ? Ba2 : Ba3;
    } else {
        W  = (wsel == 0) ? Wb0 : (wsel == 1) ? Wb1 : (wsel == 2) ? Wb2 : Wb3;
        Bv = (wsel == 0) ? Bb0 : (wsel == 1) ? Bb1 : (wsel == 2) ? Bb2 : Bb3;
    }
    unsigned short* Wt = (layer == 0) ? Wt1 : Wt2;
    float* bfused = (layer == 0) ? bf1 : bf2;

    int t = threadIdx.x;
    int tr = t >> 4;
    int tc4 = (t & 15) * 4;
    #pragma unroll
    for (int r = 0; r < 64; r += 16) {
        float4 v = *(const float4*)&W[(size_t)(kt * 64 + tr + r) * 256 + ct * 64 + tc4];
        tile[tr + r][tc4 + 0] = v.x;
        tile[tr + r][tc4 + 1] = v.y;
        tile[tr + r][tc4 + 2] = v.z;
        tile[tr + r][tc4 + 3] = v.w;
    }
    __syncthreads();
    #pragma unroll
    for (int r = 0; r < 64; r += 16) {
        int nr = tr + r;
        ushort4 o;
        o.x = f2h(tile[tc4 + 0][nr]);
        o.y = f2h(tile[tc4 + 1][nr]);
        o.z = f2h(tile[tc4 + 2][nr]);
        o.w = f2h(tile[tc4 + 3][nr]);
        *(ushort4*)&Wt[(size_t)(wsel * 256 + ct * 64 + nr) * 256 + kt * 64 + tc4] = o;
    }
    if (kt == 0 && t < 64) bfused[wsel * 256 + ct * 64 + t] = Bv[ct * 64 + t];
}

// ---------------- CSR scan (parallel 3-kernel chain) ----------------

__global__ __launch_bounds__(256) void k_blocksum(const int* __restrict__ deg, int* __restrict__ bsum) {
    __shared__ int sh[256];
    int i = blockIdx.x * 256 + threadIdx.x;
    sh[threadIdx.x] = (i < NODES) ? deg[i] : 0;
    __syncthreads();
    for (int off = 128; off > 0; off >>= 1) {
        if (threadIdx.x < off) sh[threadIdx.x] += sh[threadIdx.x + off];
        __syncthreads();
    }
    if (threadIdx.x == 0) bsum[blockIdx.x] = sh[0];
}

__global__ __launch_bounds__(128) void k_scanb(const int* __restrict__ bsum, int* __restrict__ bbase, int nb) {
    __shared__ int sh[128];
    int t = threadIdx.x;
    int v = (t < nb) ? bsum[t] : 0;
    sh[t] = v;
    __syncthreads();
    for (int off = 1; off < 128; off <<= 1) {
        int add = (t >= off) ? sh[t - off] : 0;
        __syncthreads();
        sh[t] += add;
        __syncthreads();
    }
    if (t < nb) bbase[t] = sh[t] - v;   // exclusive
}

__global__ __launch_bounds__(256) void k_localscan(const int* __restrict__ deg, const int* __restrict__ bbase,
                                                   int* __restrict__ rowptr, int* __restrict__ cursor) {
    __shared__ int sh[256];
    int i = blockIdx.x * 256 + threadIdx.x;
    int v = (i < NODES) ? deg[i] : 0;
    sh[threadIdx.x] = v;
    __syncthreads();
    for (int off = 1; off < 256; off <<= 1) {
        int add = (threadIdx.x >= off) ? sh[threadIdx.x - off] : 0;
        __syncthreads();
        sh[threadIdx.x] += add;
        __syncthreads();
    }
    if (i < NODES) {
        int p = bbase[blockIdx.x] + sh[threadIdx.x] - v;  // exclusive
        rowptr[i] = p;
        cursor[i] = p;
    }
}

// ---------------- GEMM body (shared by k_big's GEMM path and k_gemm_f16) ----------------
// XCD swizzle + T2 pre-swizzled-global LDS anti-conflict (r14, verified).

#define CS 136   // padded LDS stride (ushorts) for the 128x128 C tile
#define GB_GEMM 1880            // 235 row x 8 col

__device__ __forceinline__ void gemm_body(
    unsigned short* sbuf,
    const unsigned short* __restrict__ A,
    const unsigned short* __restrict__ Wt,
    const float* __restrict__ bias,
    unsigned short* __restrict__ QS,
    unsigned short* __restrict__ K16,
    unsigned char* __restrict__ V8, int M, int bid)
{
    unsigned short* As = sbuf;                  // 128*64
    unsigned short* Bs = sbuf + 8192;           // 128*64
    int tid = threadIdx.x;
    int lane = tid & 63;
    int wave = tid >> 6;
    int wm = wave & 1, wn = wave >> 1;

    int sbid = (bid & 7) * 235 + (bid >> 3);
    int row0 = (sbid >> 3) * 128;
    int n0 = (sbid & 7) * 128;

    f32x4 acc[4][4] = {};

    for (int k0 = 0; k0 < 256; k0 += 64) {
        #pragma unroll
        for (int w = 0; w < 4; w++) {
            int c = w * 256 + tid;
            int row = c >> 3;
            int cole = (((c & 7) ^ (row & 7)) * 8);  // pre-swizzled source column (T2/m173)
            int ar = row0 + row; if (ar >= M) ar = M - 1;
            gload_lds16(&A[(size_t)ar * 256 + k0 + cole], &As[w * 2048 + tid * 8]);
            gload_lds16(&Wt[(size_t)(n0 + row) * 256 + k0 + cole], &Bs[w * 2048 + tid * 8]);
        }
        __syncthreads();
        int rsel = lane & 15;
        int qk = lane >> 4;
        int key = lane & 7;
        #pragma unroll
        for (int kh = 0; kh < 2; kh++) {
            f16x8 af[4], bfr[4];
            #pragma unroll
            for (int t = 0; t < 4; t++) {
                int ch = ((kh * 4 + qk) ^ key) * 8;   // swizzled chunk (same involution)
                af[t]  = *reinterpret_cast<const f16x8*>(&As[(wm * 64 + t * 16 + rsel) * 64 + ch]);
                bfr[t] = *reinterpret_cast<const f16x8*>(&Bs[(wn * 64 + t * 16 + rsel) * 64 + ch]);
            }
            #pragma unroll
            for (int mt = 0; mt < 4; mt++)
                #pragma unroll
                for (int nt = 0; nt < 4; nt++)
                    acc[mt][nt] = __builtin_amdgcn_mfma_f32_16x16x32_f16(af[mt], bfr[nt], acc[mt][nt], 0, 0, 0);
        }
        __syncthreads();
    }

    // epilogue (C/D map: col=lane&15, row=(lane>>4)*4+reg)
    int crow = (lane >> 4) * 4;
    int ccol = lane & 15;
    #pragma unroll
    for (int mt = 0; mt < 4; mt++) {
        int lrow = wm * 64 + mt * 16 + crow;
        #pragma unroll
        for (int nt = 0; nt < 4; nt++) {
            int lcol = wn * 64 + nt * 16 + ccol;
            float bv = bias[n0 + lcol];
            #pragma unroll
            for (int r = 0; r < 4; r++)
                sbuf[(lrow + r) * CS + lcol] = f2h(acc[mt][nt][r] + bv);
        }
    }
    __syncthreads();
    int chunk = tid & 15;
    int rbase = tid >> 4;
    if (n0 < 256 || n0 >= 768) {
        int cbase = (n0 < 256) ? n0 : (n0 - 512);
        #pragma unroll
        for (int g = 0; g < 8; g++) {
            int row_l = g * 16 + rbase;
            int gr = row0 + row_l;
            if (gr < M) {
                uint4 val = *(const uint4*)&sbuf[row_l * CS + chunk * 8];
                *(uint4*)&QS[(size_t)gr * QS_W + cbase + chunk * 8] = val;
            }
        }
    } else if (n0 < 512) {
        int cbase = n0 - 256;
        #pragma unroll
        for (int g = 0; g < 8; g++) {
            int row_l = g * 16 + rbase;
            int gr = row0 + row_l;
            if (gr < M) {
                uint4 val = *(const uint4*)&sbuf[row_l * CS + chunk * 8];
                *(uint4*)&K16[(size_t)gr * K_W + cbase + chunk * 8] = val;
            }
        }
    } else {
        int cbase = n0 - 512;
        #pragma unroll
        for (int g = 0; g < 8; g++) {
            int row_l = g * 16 + rbase;
            int gr = row0 + row_l;
            if (gr < M) {
                uint4 val = *(const uint4*)&sbuf[row_l * CS + chunk * 8];
                uint2 enc = enc8(val);
                *(uint2*)&V8[(size_t)gr * KV_W + cbase + chunk * 8] = enc;
            }
        }
    }
}

// k_big: blocks [0,1880) = GEMM layer-1; [1880, 1880+2344) = CSR fill (independent work,
// overlapped in one dispatch; fill's atomics/scatter hide under the GEMM's runtime).
__global__ __launch_bounds__(256) void k_big(
    const unsigned short* __restrict__ A,
    const unsigned short* __restrict__ Wt,
    const float* __restrict__ bias,
    unsigned short* __restrict__ QS,
    unsigned short* __restrict__ K16,
    unsigned char* __restrict__ V8, int M,
    const int* __restrict__ ei, int* __restrict__ cursor, int* __restrict__ csr_src)
{
    __shared__ unsigned short sbuf[128 * CS];
    int b = blockIdx.x;
    if (b >= GB_GEMM) {
        // ---- CSR fill
        int e = (b - GB_GEMM) * 256 + threadIdx.x;
        if (e < EDGES) {
            int s = ei[e];
            int d = ei[EDGES + e];
            int slot = atomicAdd(&cursor[d], 1);
            csr_src[slot] = s;
        }
        return;
    }
    gemm_body(sbuf, A, Wt, bias, QS, K16, V8, M, b);
}

// plain GEMM (layer 2)
__global__ __launch_bounds__(256) void k_gemm_f16(
    const unsigned short* __restrict__ A,
    const unsigned short* __restrict__ Wt,
    const float* __restrict__ bias,
    unsigned short* __restrict__ QS,
    unsigned short* __restrict__ K16,
    unsigned char* __restrict__ V8, int M)
{
    __shared__ unsigned short sbuf[128 * CS];
    gemm_body(sbuf, A, Wt, bias, QS, K16, V8, M, blockIdx.x);
}

// ---------------- attention (fp16 q/k/s, fp8 v): BIT-IDENTICAL to round 8 ----------------

__global__ __launch_bounds__(256) void k_attn_mix(const unsigned short* __restrict__ qs,
                                                  const unsigned short* __restrict__ k16,
                                                  const unsigned char* __restrict__ v8,
                                                  const int* __restrict__ rowptr,
                                                  const int* __restrict__ deg,
                                                  const int* __restrict__ csr_src,
                                                  float* __restrict__ out)
{
    int wave = threadIdx.x >> 6;
    int lane = threadIdx.x & 63;
    int node = blockIdx.x * 4 + wave;
    if (node >= NODES) return;
    int half = lane >> 5;
    int lh = lane & 31;

    const unsigned short* qrow = qs + (size_t)node * QS_W;
    uint4 qv = *(const uint4*)&qrow[lh * 8];

    int start = rowptr[node];
    int cnt = deg[node];

    float m = -INFINITY, L = 0.f;
    float acc[8] = {0.f, 0.f, 0.f, 0.f, 0.f, 0.f, 0.f, 0.f};

    if (cnt > 0) {
        int clast = cnt - 1;
        #define CPOS(p) (start + (((2 * (p) + half) > clast) ? clast : (2 * (p) + half)))
        int i0  = csr_src[CPOS(0)];
        int i1  = csr_src[CPOS(1)];
        int ixA = csr_src[CPOS(2)];
        int ixB = csr_src[CPOS(3)];
        uint4 kA, kB;
        uint2 vA, vB;
        kA = *(const uint4*)&k16[(size_t)i0 * K_W + lh * 8];
        vA = *(const uint2*)&v8[(size_t)i0 * KV_W + lh * 8];
        kB = *(const uint4*)&k16[(size_t)i1 * K_W + lh * 8];
        vB = *(const uint2*)&v8[(size_t)i1 * KV_W + lh * 8];
        int npairs = (cnt + 1) >> 1;
        for (int i = 0; i < npairs; i += 2) {
            // ========== sub-iter A ==========
            {
                const unsigned short* pkA = k16 + (size_t)ixA * K_W + lh * 8;
                const unsigned char*  pvA = v8  + (size_t)ixA * KV_W + lh * 8;
                ixA = csr_src[CPOS(i + 4)];
                float d  = fdot2(u2h2(qv.x), u2h2(kA.x), 0.f);
                d        = fdot2(u2h2(qv.y), u2h2(kA.y), d);
                float d2 = fdot2(u2h2(qv.z), u2h2(kA.z), 0.f);
                d2       = fdot2(u2h2(qv.w), u2h2(kA.w), d2);
                d += d2;
                kA = *(const uint4*)pkA;
                d = dpp_xor_add<0xB1>(d);
                d = dpp_xor_add<0x4E>(d);
                d = dpp_xor_add<0x141>(d);
                float al = d * 0.125f;
                bool valid = (2 * i + half) < cnt;
                if (valid) {
                    if (__any(al > m + 8.f)) {
                        float nm = fmaxf(m, al);
                        float sc = __expf(m - nm);
                        L *= sc;
                        #pragma unroll
                        for (int t = 0; t < 8; t++) acc[t] *= sc;
                        m = nm;
                    }
                    float p = __expf(al - m);
                    L += p;
                    float vf[8];
                    dec8(vA, vf);
                    #pragma unroll
                    for (int t = 0; t < 8; t++) acc[t] = fmaf(p, vf[t], acc[t]);
                }
                vA = *(const uint2*)pvA;
            }
            // ========== sub-iter B ==========
            {
                const unsigned short* pkB = k16 + (size_t)ixB * K_W + lh * 8;
                const unsigned char*  pvB = v8  + (size_t)ixB * KV_W + lh * 8;
                ixB = csr_src[CPOS(i + 5)];
                float d  = fdot2(u2h2(qv.x), u2h2(kB.x), 0.f);
                d        = fdot2(u2h2(qv.y), u2h2(kB.y), d);
                float d2 = fdot2(u2h2(qv.z), u2h2(kB.z), 0.f);
                d2       = fdot2(u2h2(qv.w), u2h2(kB.w), d2);
                d += d2;
                kB = *(const uint4*)pkB;
                d = dpp_xor_add<0xB1>(d);
                d = dpp_xor_add<0x4E>(d);
                d = dpp_xor_add<0x141>(d);
                float al = d * 0.125f;
                bool valid = (2 * (i + 1) + half) < cnt;
                if (valid) {
                    if (__any(al > m + 8.f)) {
                        float nm = fmaxf(m, al);
                        float sc = __expf(m - nm);
                        L *= sc;
                        #pragma unroll
                        for (int t = 0; t < 8; t++) acc[t] *= sc;
                        m = nm;
                    }
                    float p = __expf(al - m);
                    L += p;
                    float vf[8];
                    dec8(vB, vf);
                    #pragma unroll
                    for (int t = 0; t < 8; t++) acc[t] = fmaf(p, vf[t], acc[t]);
                }
                vB = *(const uint2*)pvB;
            }
        }
        #undef CPOS
    }

    // ---- merge the two half-wave softmax states
    float mo = __shfl_xor(m, 32, 64);
    float Lo = __shfl_xor(L, 32, 64);
    float nm = fmaxf(m, mo);
    float scs = (L  > 0.f) ? __expf(m  - nm) : 0.f;
    float sco = (Lo > 0.f) ? __expf(mo - nm) : 0.f;
    float Lt = fmaf(L, scs, Lo * sco);
    float inv = (Lt > 0.f) ? 1.f / Lt : 0.f;
    float t0 = fmaf(acc[0], scs, __shfl_xor(acc[0], 32, 64) * sco);
    float t1 = fmaf(acc[1], scs, __shfl_xor(acc[1], 32, 64) * sco);
    float t2 = fmaf(acc[2], scs, __shfl_xor(acc[2], 32, 64) * sco);
    float t3 = fmaf(acc[3], scs, __shfl_xor(acc[3], 32, 64) * sco);
    float t4 = fmaf(acc[4], scs, __shfl_xor(acc[4], 32, 64) * sco);
    float t5 = fmaf(acc[5], scs, __shfl_xor(acc[5], 32, 64) * sco);
    float t6 = fmaf(acc[6], scs, __shfl_xor(acc[6], 32, 64) * sco);
    float t7 = fmaf(acc[7], scs, __shfl_xor(acc[7], 32, 64) * sco);
    float w0 = half ? t4 : t0;
    float w1 = half ? t5 : t1;
    float w2 = half ? t6 : t2;
    float w3 = half ? t7 : t3;
    ushort4 sv = *(const ushort4*)&qrow[256 + lh * 8 + half * 4];
    float4 o;
    o.x = fmaf(w0, inv, h2f(sv.x));
    o.y = fmaf(w1, inv, h2f(sv.y));
    o.z = fmaf(w2, inv, h2f(sv.z));
    o.w = fmaf(w3, inv, h2f(sv.w));
    *(float4*)&out[(size_t)node * OUT_W + lh * 8 + half * 4] = o;
}

// ---------------- BatchNorm ----------------

__global__ __launch_bounds__(256) void k_bnstats(const float* __restrict__ h,
                                                 float* __restrict__ sum, float* __restrict__ sumsq) {
    int col = threadIdx.x;
    int r0 = blockIdx.x * 64;
    int r1 = min(r0 + 64, NODES);
    float s = 0.f, s2 = 0.f;
    for (int r = r0; r < r1; r++) {
        float v = h[(size_t)r * OUT_W + col];
        s += v; s2 += v * v;
    }
    atomicAdd(&sum[col], s);
    atomicAdd(&sumsq[col], s2);
}

__device__ __forceinline__ float4 bn_scale4(const float* sum, const float* sumsq,
                                            const float* g, const float* be,
                                            int col, float4* shift) {
    float4 s  = *(const float4*)&sum[col];
    float4 s2 = *(const float4*)&sumsq[col];
    float4 gv = *(const float4*)&g[col];
    float4 bv = *(const float4*)&be[col];
    const float invN = 1.0f / NODES;
    float4 sc, sh;
    float mean, var;
    mean = s.x * invN; var = fmaxf(s2.x * invN - mean * mean, 0.f);
    sc.x = gv.x * rsqrtf(var + BN_EPS); sh.x = bv.x - mean * sc.x;
    mean = s.y * invN; var = fmaxf(s2.y * invN - mean * mean, 0.f);
    sc.y = gv.y * rsqrtf(var + BN_EPS); sh.y = bv.y - mean * sc.y;
    mean = s.z * invN; var = fmaxf(s2.z * invN - mean * mean, 0.f);
    sc.z = gv.z * rsqrtf(var + BN_EPS); sh.z = bv.z - mean * sc.z;
    mean = s.w * invN; var = fmaxf(s2.w * invN - mean * mean, 0.f);
    sc.w = gv.w * rsqrtf(var + BN_EPS); sh.w = bv.w - mean * sc.w;
    *shift = sh;
    return sc;
}

__global__ __launch_bounds__(256) void k_bnapply_f16(const float* __restrict__ h,
                                                     const float* __restrict__ sum,
                                                     const float* __restrict__ sumsq,
                                                     const float* __restrict__ g,
                                                     const float* __restrict__ be,
                                                     unsigned short* __restrict__ out) {
    int idx = blockIdx.x * 256 + threadIdx.x;
    int base = idx * 4;
    int col = base & (OUT_W - 1);
    float4 sh;
    float4 sc = bn_scale4(sum, sumsq, g, be, col, &sh);
    float4 v = *(const float4*)&h[base];
    float4 o;
    o.x = v.x * sc.x + sh.x; o.x = (o.x >= 0.f) ? o.x : 0.1f * o.x;
    o.y = v.y * sc.y + sh.y; o.y = (o.y >= 0.f) ? o.y : 0.1f * o.y;
    o.z = v.z * sc.z + sh.z; o.z = (o.z >= 0.f) ? o.z : 0.1f * o.z;
    o.w = v.w * sc.w + sh.w; o.w = (o.w >= 0.f) ? o.w : 0.1f * o.w;
    ushort4 u; u.x = f2h(o.x); u.y = f2h(o.y); u.z = f2h(o.z); u.w = f2h(o.w);
    *(ushort4*)&out[base] = u;
}

__global__ __launch_bounds__(256) void k_bnapply(const float* __restrict__ h,
                                                 const float* __restrict__ sum,
                                                 const float* __restrict__ sumsq,
                                                 const float* __restrict__ g,
                                                 const float* __restrict__ be,
                                                 float* __restrict__ out) {
    int idx = blockIdx.x * 256 + threadIdx.x;
    int base = idx * 4;
    int col = base & (OUT_W - 1);
    float4 sh;
    float4 sc = bn_scale4(sum, sumsq, g, be, col, &sh);
    float4 v = *(const float4*)&h[base];
    float4 o;
    o.x = v.x * sc.x + sh.x; o.x = (o.x >= 0.f) ? o.x : 0.1f * o.x;
    o.y = v.y * sc.y + sh.y; o.y = (o.y >= 0.f) ? o.y : 0.1f * o.y;
    o.z = v.z * sc.z + sh.z; o.z = (o.z >= 0.f) ? o.z : 0.1f * o.z;
    o.w = v.w * sc.w + sh.w; o.w = (o.w >= 0.f) ? o.w : 0.1f * o.w;
    *(float4*)&out[base] = o;
}

// ---------------- launch ----------------
// 13 dispatches. Overlap fusions (this round's variable): k_pre = castAW+count (independent);
// k_big = GEMM1+fill (independent). All arithmetic byte-identical to r14.

extern "C" void kernel_launch(void* const* d_in, const int* in_sizes, int n_in,
                              void* d_out, int out_size, void* d_ws, size_t ws_size,
                              hipStream_t stream) {
    const float* x  = (const float*)d_in[0];
    const int*   ei = (const int*)d_in[1];
    const float* w1[4] = {(const float*)d_in[2], (const float*)d_in[4], (const float*)d_in[6], (const float*)d_in[8]};
    const float* b1[4] = {(const float*)d_in[3], (const float*)d_in[5], (const float*)d_in[7], (const float*)d_in[9]};
    const float* g1  = (const float*)d_in[10];
    const float* be1 = (const float*)d_in[11];
    const float* w2[4] = {(const float*)d_in[12], (const float*)d_in[14], (const float*)d_in[16], (const float*)d_in[18]};
    const float* b2[4] = {(const float*)d_in[13], (const float*)d_in[15], (const float*)d_in[17], (const float*)d_in[19]};
    const float* g2  = (const float*)d_in[20];
    const float* be2 = (const float*)d_in[21];

    char* ws = (char*)d_ws;
    unsigned short* qsb    = (unsigned short*)(ws);                 // 30,720,000 (fp16 [q|s])
    unsigned short* k16b   = (unsigned short*)(ws + 30720000);      // 15,360,000 (fp16 k)
    unsigned char*  v8b    = (unsigned char*)(ws + 46080000);       //  7,680,000 (fp8 v)
    float*          h1     = (float*)(ws + 53760000);               // 30,720,000
    unsigned short* abuf   = (unsigned short*)(ws + 84480000);      // 15,360,000 (fp16 GEMM input)
    unsigned short* wt1    = (unsigned short*)(ws + 99840000);      // 524,288
    unsigned short* wt2    = (unsigned short*)(ws + 100364288);     // 524,288
    float*          b1f    = (float*)(ws + 100888576);              // 4,096
    float*          b2f    = (float*)(ws + 100892672);              // 4,096
    int*            deg    = (int*)  (ws + 100896768);              // 120,000
    int*            rowptr = (int*)  (ws + 101016768);              // 120,000
    int*            cursor = (int*)  (ws + 101136768);              // 120,000
    int*            csr    = (int*)  (ws + 101256768);              // 2,400,000
    int*            bsum   = (int*)  (ws + 103656768);              // 512
    int*            bbase  = (int*)  (ws + 103657280);              // 512
    float*          sum1   = (float*)(ws + 103657792);              // 4 x 1024 B contiguous
    float*          sq1    = (float*)(ws + 103658816);
    float*          sum2   = (float*)(ws + 103659840);
    float*          sq2    = (float*)(ws + 103660864);

    const int NB = (NODES + 255) / 256;       // 118

    k_init <<<NB, 256, 0, stream>>>(deg, sum1);      // deg + all 4 BN sum arrays

    // fused: W transpose-cast + A cast + edge count (count needs deg zeroed -> after k_init)
    k_pre  <<<PRE_WBLK + PRE_ABLK + PRE_CBLK, 256, 0, stream>>>(
        x, abuf, ei, deg,
        w1[0], w1[1], w1[2], w1[3], b1[0], b1[1], b1[2], b1[3],
        w2[0], w2[1], w2[2], w2[3], b2[0], b2[1], b2[2], b2[3],
        wt1, b1f, wt2, b2f);

    // CSR scan chain
    k_blocksum <<<NB, 256, 0, stream>>>(deg, bsum);
    k_scanb    <<<1, 128, 0, stream>>>(bsum, bbase, NB);
    k_localscan<<<NB, 256, 0, stream>>>(deg, bbase, rowptr, cursor);

    const int ANB = NODES / 4;                // 7500
    const int APB = (NODES * OUT_W / 4) / 256;// 7500
    const int SNB = (NODES + 63) / 64;        // 469

    // layer 1: GEMM1 + CSR fill overlapped in one dispatch
    k_big        <<<GB_GEMM + PRE_CBLK, 256, 0, stream>>>(abuf, wt1, b1f, qsb, k16b, v8b, NODES,
                                                          ei, cursor, csr);
    k_attn_mix   <<<ANB, 256, 0, stream>>>(qsb, k16b, v8b, rowptr, deg, csr, h1);
    k_bnstats    <<<SNB, 256, 0, stream>>>(h1, sum1, sq1);
    k_bnapply_f16<<<APB, 256, 0, stream>>>(h1, sum1, sq1, g1, be1, abuf);

    // layer 2
    k_gemm_f16   <<<GB_GEMM, 256, 0, stream>>>(abuf, wt2, b2f, qsb, k16b, v8b, NODES);
    k_attn_mix   <<<ANB, 256, 0, stream>>>(qsb, k16b, v8b, rowptr, deg, csr, h1);
    k_bnstats    <<<SNB, 256, 0, stream>>>(h1, sum2, sq2);
    k_bnapply    <<<APB, 256, 0, stream>>>(h1, sum2, sq2, g2, be2, (float*)d_out);
}